// Round 1
// baseline (4999.488 us; speedup 1.0000x reference)
//
#include <hip/hip_runtime.h>
#include <hip/hip_bf16.h>
#include <math.h>

#define HEADS 16
#define NCL 256
#define BB 8
#define NN 4096
#define DD 1024
#define DH 64
#define MM (BB*NN)   // 32768

// ---------------- kernel 1: cluster counts (int atomics = deterministic) ----
__global__ __launch_bounds__(256) void count_k(const int* __restrict__ cluster,
                                               int* __restrict__ counts) {
    int i = blockIdx.x * 256 + threadIdx.x;
    if (i < BB * NN) {
        int b = i / NN;
        atomicAdd(counts + b * NCL + cluster[i], 1);
    }
}

// ---------------- kernel 2/3/6: fp32 SGEMM -------------------------------
// C[M x N] = A[M x K] @ B[K x N] (+bias). 128x128 tile, BK=8, 256 threads,
// 8x8 per thread in split quadrants (tm, tm+64) x (tn, tn+64) so LDS reads
// are <=2-way bank aliased (free on CDNA4).
template<int BIAS>
__global__ __launch_bounds__(256) void sgemm_k(const float* __restrict__ A, int lda,
                                               const float* __restrict__ Bw, int ldb,
                                               float* __restrict__ Cc, int ldc,
                                               const float* __restrict__ bias,
                                               int Kdim) {
    __shared__ float As[8][132];   // [k][m], +4 pad
    __shared__ float Bs[8][132];   // [k][n], +4 pad

    const int tid = threadIdx.x;
    const int tm = (tid >> 4) * 4;      // 0..60
    const int tn = (tid & 15) * 4;      // 0..60
    const size_t row0 = (size_t)blockIdx.y * 128;
    const int col0 = blockIdx.x * 128;

    const int ar = tid >> 1;            // 0..127 (A tile row)
    const int ak = (tid & 1) * 4;       // 0 or 4 (A tile col)
    const int br = tid >> 5;            // 0..7   (B tile row)
    const int bc = (tid & 31) * 4;      // 0..124 (B tile col)

    const float* Ap = A + (row0 + ar) * (size_t)lda + ak;
    const float* Bp = Bw + (size_t)br * ldb + col0 + bc;

    float acc[8][8];
#pragma unroll
    for (int i = 0; i < 8; ++i)
#pragma unroll
        for (int j = 0; j < 8; ++j) acc[i][j] = 0.f;

    for (int k0 = 0; k0 < Kdim; k0 += 8) {
        float4 av = *(const float4*)(Ap + k0);
        float4 bv = *(const float4*)(Bp + (size_t)k0 * ldb);
        __syncthreads();
        As[ak + 0][ar] = av.x;
        As[ak + 1][ar] = av.y;
        As[ak + 2][ar] = av.z;
        As[ak + 3][ar] = av.w;
        *(float4*)&Bs[br][bc] = bv;
        __syncthreads();
#pragma unroll
        for (int kk = 0; kk < 8; ++kk) {
            float a[8], b[8];
            *(float4*)&a[0] = *(const float4*)&As[kk][tm];
            *(float4*)&a[4] = *(const float4*)&As[kk][tm + 64];
            *(float4*)&b[0] = *(const float4*)&Bs[kk][tn];
            *(float4*)&b[4] = *(const float4*)&Bs[kk][tn + 64];
#pragma unroll
            for (int i = 0; i < 8; ++i)
#pragma unroll
                for (int j = 0; j < 8; ++j)
                    acc[i][j] = fmaf(a[i], b[j], acc[i][j]);
        }
    }

#pragma unroll
    for (int ih = 0; ih < 2; ++ih)
#pragma unroll
        for (int i = 0; i < 4; ++i) {
            size_t r = row0 + tm + ih * 64 + i;
            float* cp = Cc + r * (size_t)ldc + col0;
#pragma unroll
            for (int jh = 0; jh < 2; ++jh) {
                int cc = tn + jh * 64;
                float4 o;
                o.x = acc[ih * 4 + i][jh * 4 + 0];
                o.y = acc[ih * 4 + i][jh * 4 + 1];
                o.z = acc[ih * 4 + i][jh * 4 + 2];
                o.w = acc[ih * 4 + i][jh * 4 + 3];
                if (BIAS) {
                    const float* bp = bias + col0 + cc;
                    o.x += bp[0]; o.y += bp[1]; o.z += bp[2]; o.w += bp[3];
                }
                *(float4*)(cp + cc) = o;
            }
        }
}

// ---------------- kernel 4: cluster segment-mean of k and v ---------------
// one block per (b, c); fixed token order -> deterministic fp32 sums.
__global__ __launch_bounds__(256) void center_k(const float* __restrict__ Y,
                                                const int* __restrict__ cluster,
                                                const int* __restrict__ counts,
                                                float* __restrict__ kc,
                                                float* __restrict__ vc) {
    __shared__ int cl[NN];   // 16 KB
    const int bb = blockIdx.x >> 8;     // / NCL
    const int c = blockIdx.x & (NCL - 1);
    const int tid = threadIdx.x;

    for (int i = tid; i < NN; i += 256) cl[i] = cluster[bb * NN + i];
    __syncthreads();

    float ka[4] = {0.f, 0.f, 0.f, 0.f};
    float va[4] = {0.f, 0.f, 0.f, 0.f};
    for (int t = 0; t < NN; ++t) {
        if (cl[t] == c) {
            const float* yr = Y + ((size_t)bb * NN + t) * 3072;
#pragma unroll
            for (int j = 0; j < 4; ++j) {
                ka[j] += yr[1024 + tid + 256 * j];
                va[j] += yr[2048 + tid + 256 * j];
            }
        }
    }
    int cnt = counts[bb * NCL + c];
    float inv = cnt > 0 ? 1.f / (float)cnt : 0.f;
    size_t o = ((size_t)bb * NCL + c) * DD;
#pragma unroll
    for (int j = 0; j < 4; ++j) {
        kc[o + tid + 256 * j] = ka[j] * inv;
        vc[o + tid + 256 * j] = va[j] * inv;
    }
}

// ---------------- kernel 5: attention over cluster centers ----------------
// grid (n/256, h, b); 256 threads = 256 token rows. Online weighted softmax:
// attn_c = counts_c * exp(s_c) / sum(counts * exp(s)). In-place: q slot of Y
// becomes the attention output (each thread reads its own q row first).
__global__ __launch_bounds__(256) void attn_k(float* __restrict__ Y,
                                              const float* __restrict__ kc,
                                              const float* __restrict__ vc,
                                              const int* __restrict__ counts) {
    __shared__ float kcs[NCL][DH];   // 64 KB
    __shared__ float vcs[NCL][DH];   // 64 KB
    __shared__ float cw[NCL];        // 1 KB

    const int ntile = blockIdx.x, hh = blockIdx.y, bb = blockIdx.z;
    const int tid = threadIdx.x;

    const float* kcb = kc + ((size_t)bb * NCL) * DD + hh * DH;
    const float* vcb = vc + ((size_t)bb * NCL) * DD + hh * DH;
    for (int i = tid; i < NCL * DH / 4; i += 256) {
        int c = i >> 4;
        int e4 = (i & 15) * 4;
        *(float4*)&kcs[c][e4] = *(const float4*)(kcb + (size_t)c * DD + e4);
        *(float4*)&vcs[c][e4] = *(const float4*)(vcb + (size_t)c * DD + e4);
    }
    for (int i = tid; i < NCL; i += 256) cw[i] = (float)counts[bb * NCL + i];
    __syncthreads();

    const int r = ntile * 256 + tid;
    float* yrow = Y + ((size_t)bb * NN + r) * 3072 + hh * DH;

    float q[DH];
#pragma unroll
    for (int e = 0; e < DH; e += 4) *(float4*)&q[e] = *(const float4*)(yrow + e);

    float acc[DH];
#pragma unroll
    for (int e = 0; e < DH; ++e) acc[e] = 0.f;

    float m = -INFINITY, l = 0.f;
    for (int c = 0; c < NCL; ++c) {
        float w = cw[c];
        if (w == 0.f) continue;       // block-uniform branch
        float s0 = 0.f, s1 = 0.f, s2 = 0.f, s3 = 0.f;
#pragma unroll
        for (int e = 0; e < DH; e += 4) {
            s0 = fmaf(q[e + 0], kcs[c][e + 0], s0);
            s1 = fmaf(q[e + 1], kcs[c][e + 1], s1);
            s2 = fmaf(q[e + 2], kcs[c][e + 2], s2);
            s3 = fmaf(q[e + 3], kcs[c][e + 3], s3);
        }
        float s = ((s0 + s1) + (s2 + s3)) * 0.125f;   // 1/sqrt(64)
        if (s > m) {
            float corr = __expf(m - s);               // exp(-inf)=0 first time
            l *= corr;
#pragma unroll
            for (int e = 0; e < DH; ++e) acc[e] *= corr;
            m = s;
        }
        float p = w * __expf(s - m);
        l += p;
#pragma unroll
        for (int e = 0; e < DH; ++e) acc[e] = fmaf(p, vcs[c][e], acc[e]);
    }

    float invl = 1.f / l;
#pragma unroll
    for (int e = 0; e < DH; e += 4) {
        float4 o;
        o.x = acc[e + 0] * invl;
        o.y = acc[e + 1] * invl;
        o.z = acc[e + 2] * invl;
        o.w = acc[e + 3] * invl;
        *(float4*)(yrow + e) = o;
    }
}

// ---------------- launcher -------------------------------------------------
extern "C" void kernel_launch(void* const* d_in, const int* in_sizes, int n_in,
                              void* d_out, int out_size, void* d_ws, size_t ws_size,
                              hipStream_t stream) {
    const int* cluster  = (const int*)d_in[0];
    const float* x      = (const float*)d_in[1];
    const float* w_q    = (const float*)d_in[2];
    const float* w_kv   = (const float*)d_in[3];
    const float* w_proj = (const float*)d_in[4];
    const float* b_proj = (const float*)d_in[5];
    float* out = (float*)d_out;

    // workspace layout: Y (M x 3072: qproj|k|v, attn output overwrites qproj)
    // then k_center, v_center (b*C*d each), then counts (b*C ints).
    char* ws = (char*)d_ws;
    float* Y = (float*)ws;
    size_t ybytes = (size_t)MM * 3072 * sizeof(float);
    float* kc = (float*)(ws + ybytes);
    float* vc = kc + (size_t)BB * NCL * DD;
    int* counts = (int*)(vc + (size_t)BB * NCL * DD);

    hipMemsetAsync(counts, 0, BB * NCL * sizeof(int), stream);
    count_k<<<MM / 256, 256, 0, stream>>>(cluster, counts);

    dim3 gq(DD / 128, MM / 128);
    sgemm_k<0><<<gq, 256, 0, stream>>>(x, DD, w_q, DD, Y, 3072, nullptr, DD);
    dim3 gkv(2 * DD / 128, MM / 128);
    sgemm_k<0><<<gkv, 256, 0, stream>>>(x, DD, w_kv, 2 * DD, Y + DD, 3072, nullptr, DD);

    center_k<<<BB * NCL, 256, 0, stream>>>(Y, cluster, counts, kc, vc);

    dim3 ga(NN / 256, HEADS, BB);
    attn_k<<<ga, 256, 0, stream>>>(Y, kc, vc, counts);

    dim3 gp(DD / 128, MM / 128);
    sgemm_k<1><<<gp, 256, 0, stream>>>(Y, 3072, w_proj, DD, out, DD, b_proj, DD);
}

// Round 2
// 3878.237 us; speedup vs baseline: 1.2891x; 1.2891x over previous
//
#include <hip/hip_runtime.h>
#include <hip/hip_bf16.h>
#include <math.h>

#define HEADS 16
#define NCL 256
#define BB 8
#define NN 4096
#define DD 1024
#define DH 64
#define MM (BB*NN)   // 32768

// ---------------- kernel 1: cluster counts (int atomics = deterministic) ----
__global__ __launch_bounds__(256) void count_k(const int* __restrict__ cluster,
                                               int* __restrict__ counts) {
    int i = blockIdx.x * 256 + threadIdx.x;
    if (i < BB * NN) {
        int b = i / NN;
        atomicAdd(counts + b * NCL + cluster[i], 1);
    }
}

// ---------------- kernel 2/3/6: fp32 SGEMM -------------------------------
// C[M x N] = A[M x K] @ B[K x N] (+bias). 128x128 tile, BK=8, 256 threads,
// 8x8 per thread in split quadrants (tm, tm+64) x (tn, tn+64) so LDS reads
// are <=2-way bank aliased (free on CDNA4).
template<int BIAS>
__global__ __launch_bounds__(256) void sgemm_k(const float* __restrict__ A, int lda,
                                               const float* __restrict__ Bw, int ldb,
                                               float* __restrict__ Cc, int ldc,
                                               const float* __restrict__ bias,
                                               int Kdim) {
    __shared__ float As[8][132];   // [k][m], +4 pad
    __shared__ float Bs[8][132];   // [k][n], +4 pad

    const int tid = threadIdx.x;
    const int tm = (tid >> 4) * 4;      // 0..60
    const int tn = (tid & 15) * 4;      // 0..60
    const size_t row0 = (size_t)blockIdx.y * 128;
    const int col0 = blockIdx.x * 128;

    const int ar = tid >> 1;            // 0..127 (A tile row)
    const int ak = (tid & 1) * 4;       // 0 or 4 (A tile col)
    const int br = tid >> 5;            // 0..7   (B tile row)
    const int bc = (tid & 31) * 4;      // 0..124 (B tile col)

    const float* Ap = A + (row0 + ar) * (size_t)lda + ak;
    const float* Bp = Bw + (size_t)br * ldb + col0 + bc;

    float acc[8][8];
#pragma unroll
    for (int i = 0; i < 8; ++i)
#pragma unroll
        for (int j = 0; j < 8; ++j) acc[i][j] = 0.f;

    for (int k0 = 0; k0 < Kdim; k0 += 8) {
        float4 av = *(const float4*)(Ap + k0);
        float4 bv = *(const float4*)(Bp + (size_t)k0 * ldb);
        __syncthreads();
        As[ak + 0][ar] = av.x;
        As[ak + 1][ar] = av.y;
        As[ak + 2][ar] = av.z;
        As[ak + 3][ar] = av.w;
        *(float4*)&Bs[br][bc] = bv;
        __syncthreads();
#pragma unroll
        for (int kk = 0; kk < 8; ++kk) {
            float a[8], b[8];
            *(float4*)&a[0] = *(const float4*)&As[kk][tm];
            *(float4*)&a[4] = *(const float4*)&As[kk][tm + 64];
            *(float4*)&b[0] = *(const float4*)&Bs[kk][tn];
            *(float4*)&b[4] = *(const float4*)&Bs[kk][tn + 64];
#pragma unroll
            for (int i = 0; i < 8; ++i)
#pragma unroll
                for (int j = 0; j < 8; ++j)
                    acc[i][j] = fmaf(a[i], b[j], acc[i][j]);
        }
    }

#pragma unroll
    for (int ih = 0; ih < 2; ++ih)
#pragma unroll
        for (int i = 0; i < 4; ++i) {
            size_t r = row0 + tm + ih * 64 + i;
            float* cp = Cc + r * (size_t)ldc + col0;
#pragma unroll
            for (int jh = 0; jh < 2; ++jh) {
                int cc = tn + jh * 64;
                float4 o;
                o.x = acc[ih * 4 + i][jh * 4 + 0];
                o.y = acc[ih * 4 + i][jh * 4 + 1];
                o.z = acc[ih * 4 + i][jh * 4 + 2];
                o.w = acc[ih * 4 + i][jh * 4 + 3];
                if (BIAS) {
                    const float* bp = bias + col0 + cc;
                    o.x += bp[0]; o.y += bp[1]; o.z += bp[2]; o.w += bp[3];
                }
                *(float4*)(cp + cc) = o;
            }
        }
}

// ---------------- kernel 4: cluster segment-mean of k and v ---------------
// one block per (b, c); fixed token order -> deterministic fp32 sums.
__global__ __launch_bounds__(256) void center_k(const float* __restrict__ Y,
                                                const int* __restrict__ cluster,
                                                const int* __restrict__ counts,
                                                float* __restrict__ kc,
                                                float* __restrict__ vc) {
    __shared__ int cl[NN];   // 16 KB
    const int bb = blockIdx.x >> 8;     // / NCL
    const int c = blockIdx.x & (NCL - 1);
    const int tid = threadIdx.x;

    for (int i = tid; i < NN; i += 256) cl[i] = cluster[bb * NN + i];
    __syncthreads();

    float ka[4] = {0.f, 0.f, 0.f, 0.f};
    float va[4] = {0.f, 0.f, 0.f, 0.f};
    for (int t = 0; t < NN; ++t) {
        if (cl[t] == c) {
            const float* yr = Y + ((size_t)bb * NN + t) * 3072;
#pragma unroll
            for (int j = 0; j < 4; ++j) {
                ka[j] += yr[1024 + tid + 256 * j];
                va[j] += yr[2048 + tid + 256 * j];
            }
        }
    }
    int cnt = counts[bb * NCL + c];
    float inv = cnt > 0 ? 1.f / (float)cnt : 0.f;
    size_t o = ((size_t)bb * NCL + c) * DD;
#pragma unroll
    for (int j = 0; j < 4; ++j) {
        kc[o + tid + 256 * j] = ka[j] * inv;
        vc[o + tid + 256 * j] = va[j] * inv;
    }
}

// ---------------- kernel 5: attention over cluster centers ----------------
// grid (n/256, h, b); 256 threads = 256 token rows, 1 token/thread.
// Center rows are block-uniform addresses -> compiler scalarizes to s_load
// (SGPR broadcast into v_fma). No LDS -> occupancy is VGPR-bound (~3 w/SIMD).
// Raw weighted softmax (no max subtraction): scores are ~N(0, 0.25), so
// exp() cannot overflow; attn_c = cnt_c * exp(s_c) / sum(cnt * exp(s)).
// In-place: q slot of Y becomes the attention output.
__global__ __launch_bounds__(256) void attn_k(float* __restrict__ Y,
                                              const float* __restrict__ kc,
                                              const float* __restrict__ vc,
                                              const int* __restrict__ counts) {
    const int ntile = blockIdx.x, hh = blockIdx.y, bb = blockIdx.z;
    const int tid = threadIdx.x;

    const int r = ntile * 256 + tid;
    float* yrow = Y + ((size_t)bb * NN + r) * 3072 + hh * DH;

    float q[DH];
#pragma unroll
    for (int e = 0; e < DH; e += 4) *(float4*)&q[e] = *(const float4*)(yrow + e);

    float acc[DH];
#pragma unroll
    for (int e = 0; e < DH; ++e) acc[e] = 0.f;
    float l = 0.f;

    const float* kcb = kc + ((size_t)bb * NCL) * DD + hh * DH;
    const float* vcb = vc + ((size_t)bb * NCL) * DD + hh * DH;
    const int* cnt = counts + bb * NCL;

    for (int c = 0; c < NCL; ++c) {
        const float* kr = kcb + (size_t)c * DD;   // block-uniform -> s_load
        float s0 = 0.f, s1 = 0.f, s2 = 0.f, s3 = 0.f;
#pragma unroll
        for (int e = 0; e < DH; e += 4) {
            s0 = fmaf(q[e + 0], kr[e + 0], s0);
            s1 = fmaf(q[e + 1], kr[e + 1], s1);
            s2 = fmaf(q[e + 2], kr[e + 2], s2);
            s3 = fmaf(q[e + 3], kr[e + 3], s3);
        }
        float s = ((s0 + s1) + (s2 + s3)) * 0.125f;     // 1/sqrt(64)
        float p = (float)cnt[c] * __expf(s);
        l += p;
        const float* vr = vcb + (size_t)c * DD;   // block-uniform -> s_load
#pragma unroll
        for (int e = 0; e < DH; ++e) acc[e] = fmaf(p, vr[e], acc[e]);
    }

    float invl = 1.f / l;
#pragma unroll
    for (int e = 0; e < DH; e += 4) {
        float4 o;
        o.x = acc[e + 0] * invl;
        o.y = acc[e + 1] * invl;
        o.z = acc[e + 2] * invl;
        o.w = acc[e + 3] * invl;
        *(float4*)(yrow + e) = o;
    }
}

// ---------------- launcher -------------------------------------------------
extern "C" void kernel_launch(void* const* d_in, const int* in_sizes, int n_in,
                              void* d_out, int out_size, void* d_ws, size_t ws_size,
                              hipStream_t stream) {
    const int* cluster  = (const int*)d_in[0];
    const float* x      = (const float*)d_in[1];
    const float* w_q    = (const float*)d_in[2];
    const float* w_kv   = (const float*)d_in[3];
    const float* w_proj = (const float*)d_in[4];
    const float* b_proj = (const float*)d_in[5];
    float* out = (float*)d_out;

    // workspace layout: Y (M x 3072: qproj|k|v, attn output overwrites qproj)
    // then k_center, v_center (b*C*d each), then counts (b*C ints).
    char* ws = (char*)d_ws;
    float* Y = (float*)ws;
    size_t ybytes = (size_t)MM * 3072 * sizeof(float);
    float* kc = (float*)(ws + ybytes);
    float* vc = kc + (size_t)BB * NCL * DD;
    int* counts = (int*)(vc + (size_t)BB * NCL * DD);

    hipMemsetAsync(counts, 0, BB * NCL * sizeof(int), stream);
    count_k<<<MM / 256, 256, 0, stream>>>(cluster, counts);

    dim3 gq(DD / 128, MM / 128);
    sgemm_k<0><<<gq, 256, 0, stream>>>(x, DD, w_q, DD, Y, 3072, nullptr, DD);
    dim3 gkv(2 * DD / 128, MM / 128);
    sgemm_k<0><<<gkv, 256, 0, stream>>>(x, DD, w_kv, 2 * DD, Y + DD, 3072, nullptr, DD);

    center_k<<<BB * NCL, 256, 0, stream>>>(Y, cluster, counts, kc, vc);

    dim3 ga(NN / 256, HEADS, BB);
    attn_k<<<ga, 256, 0, stream>>>(Y, kc, vc, counts);

    dim3 gp(DD / 128, MM / 128);
    sgemm_k<1><<<gp, 256, 0, stream>>>(Y, 3072, w_proj, DD, out, DD, b_proj, DD);
}

// Round 3
// 3819.976 us; speedup vs baseline: 1.3088x; 1.0153x over previous
//
#include <hip/hip_runtime.h>
#include <hip/hip_bf16.h>
#include <math.h>

#define HEADS 16
#define NCL 256
#define BB 8
#define NN 4096
#define DD 1024
#define DH 64
#define MM (BB*NN)   // 32768
#define KK 1024

typedef unsigned short u16;
typedef __attribute__((ext_vector_type(8))) short s8v;     // 8 bf16 (4 VGPRs)
typedef __attribute__((ext_vector_type(4))) float f32x4;   // MFMA C/D

__device__ __forceinline__ float bf2f(u16 u) {
    union { unsigned int i; float f; } v; v.i = ((unsigned int)u) << 16; return v.f;
}
__device__ __forceinline__ u16 f2bf(float x) {   // round-to-nearest-even
    union { float f; unsigned int i; } v; v.f = x;
    unsigned int u = v.i;
    return (u16)((u + 0x7FFFu + ((u >> 16) & 1u)) >> 16);
}
__device__ __forceinline__ void gl16(const u16* g, u16* l) {
    __builtin_amdgcn_global_load_lds(
        (__attribute__((address_space(1))) void*)g,
        (__attribute__((address_space(3))) void*)l, 16, 0, 0);
}

// ---------------- cluster counts (int atomics = deterministic) -------------
__global__ __launch_bounds__(256) void count_k(const int* __restrict__ cluster,
                                               int* __restrict__ counts) {
    int i = blockIdx.x * 256 + threadIdx.x;
    if (i < BB * NN) {
        int b = i / NN;
        atomicAdd(counts + b * NCL + cluster[i], 1);
    }
}

// ---------------- x -> bf16 hi/lo split ------------------------------------
__global__ __launch_bounds__(256) void convx_k(const float* __restrict__ x,
                                               u16* __restrict__ hi,
                                               u16* __restrict__ lo) {
    size_t i = ((size_t)blockIdx.x * 256 + threadIdx.x) * 4;
    float4 v = *(const float4*)(x + i);
    ushort4 h, l;
    h.x = f2bf(v.x); l.x = f2bf(v.x - bf2f(h.x));
    h.y = f2bf(v.y); l.y = f2bf(v.y - bf2f(h.y));
    h.z = f2bf(v.z); l.z = f2bf(v.z - bf2f(h.z));
    h.w = f2bf(v.w); l.w = f2bf(v.w - bf2f(h.w));
    *(ushort4*)(hi + i) = h;
    *(ushort4*)(lo + i) = l;
}

// ---------------- weight: [K=1024][N] fp32 -> [N][K] bf16 hi/lo ------------
__global__ __launch_bounds__(256) void convw_k(const float* __restrict__ w, int N,
                                               u16* __restrict__ thi,
                                               u16* __restrict__ tlo) {
    __shared__ float t[32][33];
    const int bx = blockIdx.x, by = blockIdx.y;
    const int lx = threadIdx.x & 31, ly = threadIdx.x >> 5;   // ly 0..7
#pragma unroll
    for (int p = 0; p < 4; ++p)
        t[p * 8 + ly][lx] = w[(size_t)(by * 32 + p * 8 + ly) * N + bx * 32 + lx];
    __syncthreads();
#pragma unroll
    for (int p = 0; p < 4; ++p) {
        int n = bx * 32 + p * 8 + ly;
        int k = by * 32 + lx;
        float v = t[lx][p * 8 + ly];
        u16 h = f2bf(v);
        thi[(size_t)n * KK + k] = h;
        tlo[(size_t)n * KK + k] = f2bf(v - bf2f(h));
    }
}

// ---------------- split-bf16 MFMA GEMM -------------------------------------
// C = A@B via (Ahi+Alo)@(Bhi+Blo), dropping lo*lo (~2^-18 rel).
// A: [M][K] bf16 hi/lo, B: [N][K] bf16 hi/lo (pre-transposed weights).
// 128x128 tile, BK=32, 4 waves (2x2), 4x4 16x16x32 frags/wave, 48 MFMA/K-step.
// Staging: global_load_lds 16B, linear LDS dest; bank-conflict-free ds_read
// via quarter-XOR swizzle applied on the per-lane GLOBAL source address and
// the same involution on the read side (guide rule 21).
// OUT: 0 = f32 C, 1 = f32 C + bias, 2 = bf16 hi/lo split (ld 1024)
template<int OUT>
__global__ __launch_bounds__(256) void hgemm_k(
        const u16* __restrict__ Ahi, const u16* __restrict__ Alo,
        const u16* __restrict__ Bhi, const u16* __restrict__ Blo,
        float* __restrict__ C, int ldc, const float* __restrict__ bias,
        u16* __restrict__ Ohi, u16* __restrict__ Olo) {
    __shared__ u16 sh[4][128 * 32];   // Ahi | Alo | Bhi | Blo, 8 KB each

    const int tid = threadIdx.x;
    const int lane = tid & 63;
    const int wid = tid >> 6;
    const int wm = wid >> 1, wn = wid & 1;
    const size_t row0 = (size_t)blockIdx.y * 128;
    const size_t col0 = (size_t)blockIdx.x * 128;

    // staging map: thread t -> rows (sr, sr+64), 16B quarter sq; source quarter
    // swizzled by row so reads land conflict-free. ((sr+64)>>1)&3 == ((sr>>1)&3).
    const int sr = tid >> 2;
    const int sq = tid & 3;
    const int qs = sq ^ ((sr >> 1) & 3);

    const u16* ga0 = Ahi + (row0 + sr) * KK + qs * 8;
    const u16* ga1 = ga0 + (size_t)64 * KK;
    const u16* gA0 = Alo + (row0 + sr) * KK + qs * 8;
    const u16* gA1 = gA0 + (size_t)64 * KK;
    const u16* gb0 = Bhi + (col0 + sr) * KK + qs * 8;
    const u16* gb1 = gb0 + (size_t)64 * KK;
    const u16* gB0 = Blo + (col0 + sr) * KK + qs * 8;
    const u16* gB1 = gB0 + (size_t)64 * KK;

    u16* d = (u16*)sh + tid * 8;   // linear dest; tile stride 4096 u16, half 2048

    // read offsets: lane reads row rX, global quarter lane>>4 -> swizzled slot.
    // Swizzle bits invariant under +16*i (frag index).
    const int rA = wm * 64 + (lane & 15);
    const int rB = wn * 64 + (lane & 15);
    const int aoff = rA * 32 + (((lane >> 4) ^ ((rA >> 1) & 3)) * 8);
    const int boff = rB * 32 + (((lane >> 4) ^ ((rB >> 1) & 3)) * 8);

    f32x4 acc[4][4] = {};

    for (int k0 = 0; k0 < KK; k0 += 32) {
        gl16(ga0 + k0, d);
        gl16(ga1 + k0, d + 2048);
        gl16(gA0 + k0, d + 4096);
        gl16(gA1 + k0, d + 6144);
        gl16(gb0 + k0, d + 8192);
        gl16(gb1 + k0, d + 10240);
        gl16(gB0 + k0, d + 12288);
        gl16(gB1 + k0, d + 14336);
        __syncthreads();   // vmcnt(0) drain: staged data visible
        s8v ah[4], al[4], bh[4], bl[4];
#pragma unroll
        for (int i = 0; i < 4; ++i) {
            ah[i] = *(const s8v*)&sh[0][aoff + i * 512];
            al[i] = *(const s8v*)&sh[1][aoff + i * 512];
            bh[i] = *(const s8v*)&sh[2][boff + i * 512];
            bl[i] = *(const s8v*)&sh[3][boff + i * 512];
        }
#pragma unroll
        for (int i = 0; i < 4; ++i)
#pragma unroll
            for (int j = 0; j < 4; ++j) {
                acc[i][j] = __builtin_amdgcn_mfma_f32_16x16x32_bf16(ah[i], bh[j], acc[i][j], 0, 0, 0);
                acc[i][j] = __builtin_amdgcn_mfma_f32_16x16x32_bf16(ah[i], bl[j], acc[i][j], 0, 0, 0);
                acc[i][j] = __builtin_amdgcn_mfma_f32_16x16x32_bf16(al[i], bh[j], acc[i][j], 0, 0, 0);
            }
        __syncthreads();   // reads done before next stage overwrites
    }

    const int fr = (lane >> 4) * 4;   // C/D: row = (lane>>4)*4 + reg
    const int fc = lane & 15;         //      col = lane & 15

    if constexpr (OUT == 2) {
#pragma unroll
        for (int i = 0; i < 4; ++i)
#pragma unroll
            for (int j = 0; j < 4; ++j) {
                size_t rbase = row0 + wm * 64 + i * 16 + fr;
                size_t cidx = col0 + wn * 64 + j * 16 + fc;
#pragma unroll
                for (int g = 0; g < 4; ++g) {
                    float o = acc[i][j][g];
                    u16 h = f2bf(o);
                    u16 l2 = f2bf(o - bf2f(h));
                    size_t idx = (rbase + g) * 1024 + cidx;
                    Ohi[idx] = h;
                    Olo[idx] = l2;
                }
            }
    } else {
        float bj[4] = {0.f, 0.f, 0.f, 0.f};
        if constexpr (OUT == 1) {
#pragma unroll
            for (int j = 0; j < 4; ++j) bj[j] = bias[col0 + wn * 64 + j * 16 + fc];
        }
#pragma unroll
        for (int i = 0; i < 4; ++i)
#pragma unroll
            for (int j = 0; j < 4; ++j) {
                size_t rbase = row0 + wm * 64 + i * 16 + fr;
                size_t cidx = col0 + wn * 64 + j * 16 + fc;
#pragma unroll
                for (int g = 0; g < 4; ++g)
                    C[(rbase + g) * (size_t)ldc + cidx] = acc[i][j][g] + bj[j];
            }
    }
}

// ---------------- cluster segment-mean of k and v (Ykv stride 2048) --------
__global__ __launch_bounds__(256) void center2_k(const float* __restrict__ Ykv,
                                                 const int* __restrict__ cluster,
                                                 const int* __restrict__ counts,
                                                 float* __restrict__ kc,
                                                 float* __restrict__ vc) {
    __shared__ int cl[NN];
    const int bb = blockIdx.x >> 8;
    const int c = blockIdx.x & (NCL - 1);
    const int tid = threadIdx.x;

    for (int i = tid; i < NN; i += 256) cl[i] = cluster[bb * NN + i];
    __syncthreads();

    float ka[4] = {0.f, 0.f, 0.f, 0.f};
    float va[4] = {0.f, 0.f, 0.f, 0.f};
    for (int t = 0; t < NN; ++t) {
        if (cl[t] == c) {
            const float* yr = Ykv + ((size_t)bb * NN + t) * 2048;
#pragma unroll
            for (int j = 0; j < 4; ++j) {
                ka[j] += yr[tid + 256 * j];
                va[j] += yr[1024 + tid + 256 * j];
            }
        }
    }
    int cnt = counts[bb * NCL + c];
    float inv = cnt > 0 ? 1.f / (float)cnt : 0.f;
    size_t o = ((size_t)bb * NCL + c) * DD;
#pragma unroll
    for (int j = 0; j < 4; ++j) {
        kc[o + tid + 256 * j] = ka[j] * inv;
        vc[o + tid + 256 * j] = va[j] * inv;
    }
}

// ---------------- attention over centers: bf16 hi/lo q in, hi/lo out -------
__global__ __launch_bounds__(256) void attn_bf_k(const u16* __restrict__ Qhi,
                                                 const u16* __restrict__ Qlo,
                                                 const float* __restrict__ kc,
                                                 const float* __restrict__ vc,
                                                 const int* __restrict__ counts,
                                                 u16* __restrict__ Phi,
                                                 u16* __restrict__ Plo) {
    const int ntile = blockIdx.x, hh = blockIdx.y, bb = blockIdx.z;
    const int tid = threadIdx.x;
    const int r = ntile * 256 + tid;
    const size_t qoff = ((size_t)bb * NN + r) * 1024 + hh * DH;

    float q[DH];
#pragma unroll
    for (int e = 0; e < DH; e += 4) {
        ushort4 h4 = *(const ushort4*)(Qhi + qoff + e);
        ushort4 l4 = *(const ushort4*)(Qlo + qoff + e);
        q[e + 0] = bf2f(h4.x) + bf2f(l4.x);
        q[e + 1] = bf2f(h4.y) + bf2f(l4.y);
        q[e + 2] = bf2f(h4.z) + bf2f(l4.z);
        q[e + 3] = bf2f(h4.w) + bf2f(l4.w);
    }

    float acc[DH];
#pragma unroll
    for (int e = 0; e < DH; ++e) acc[e] = 0.f;
    float l = 0.f;

    const float* kcb = kc + ((size_t)bb * NCL) * DD + hh * DH;
    const float* vcb = vc + ((size_t)bb * NCL) * DD + hh * DH;
    const int* cnt = counts + bb * NCL;

    for (int c = 0; c < NCL; ++c) {
        const float* kr = kcb + (size_t)c * DD;   // block-uniform -> s_load
        float s0 = 0.f, s1 = 0.f, s2 = 0.f, s3 = 0.f;
#pragma unroll
        for (int e = 0; e < DH; e += 4) {
            s0 = fmaf(q[e + 0], kr[e + 0], s0);
            s1 = fmaf(q[e + 1], kr[e + 1], s1);
            s2 = fmaf(q[e + 2], kr[e + 2], s2);
            s3 = fmaf(q[e + 3], kr[e + 3], s3);
        }
        float s = ((s0 + s1) + (s2 + s3)) * 0.125f;
        float p = (float)cnt[c] * __expf(s);
        l += p;
        const float* vr = vcb + (size_t)c * DD;
#pragma unroll
        for (int e = 0; e < DH; ++e) acc[e] = fmaf(p, vr[e], acc[e]);
    }

    float invl = 1.f / l;
#pragma unroll
    for (int e = 0; e < DH; e += 4) {
        ushort4 h4, l4;
        float o0 = acc[e + 0] * invl, o1 = acc[e + 1] * invl;
        float o2 = acc[e + 2] * invl, o3 = acc[e + 3] * invl;
        h4.x = f2bf(o0); l4.x = f2bf(o0 - bf2f(h4.x));
        h4.y = f2bf(o1); l4.y = f2bf(o1 - bf2f(h4.y));
        h4.z = f2bf(o2); l4.z = f2bf(o2 - bf2f(h4.z));
        h4.w = f2bf(o3); l4.w = f2bf(o3 - bf2f(h4.w));
        *(ushort4*)(Phi + qoff + e) = h4;
        *(ushort4*)(Plo + qoff + e) = l4;
    }
}

// ================= fallback: round-2 fp32 path =============================
template<int BIAS>
__global__ __launch_bounds__(256) void sgemm_k(const float* __restrict__ A, int lda,
                                               const float* __restrict__ Bw, int ldb,
                                               float* __restrict__ Cc, int ldc,
                                               const float* __restrict__ bias,
                                               int Kdim) {
    __shared__ float As[8][132];
    __shared__ float Bs[8][132];
    const int tid = threadIdx.x;
    const int tm = (tid >> 4) * 4;
    const int tn = (tid & 15) * 4;
    const size_t row0 = (size_t)blockIdx.y * 128;
    const int col0 = blockIdx.x * 128;
    const int ar = tid >> 1;
    const int ak = (tid & 1) * 4;
    const int br = tid >> 5;
    const int bc = (tid & 31) * 4;
    const float* Ap = A + (row0 + ar) * (size_t)lda + ak;
    const float* Bp = Bw + (size_t)br * ldb + col0 + bc;
    float acc[8][8];
#pragma unroll
    for (int i = 0; i < 8; ++i)
#pragma unroll
        for (int j = 0; j < 8; ++j) acc[i][j] = 0.f;
    for (int k0 = 0; k0 < Kdim; k0 += 8) {
        float4 av = *(const float4*)(Ap + k0);
        float4 bv = *(const float4*)(Bp + (size_t)k0 * ldb);
        __syncthreads();
        As[ak + 0][ar] = av.x; As[ak + 1][ar] = av.y;
        As[ak + 2][ar] = av.z; As[ak + 3][ar] = av.w;
        *(float4*)&Bs[br][bc] = bv;
        __syncthreads();
#pragma unroll
        for (int kk = 0; kk < 8; ++kk) {
            float a[8], b[8];
            *(float4*)&a[0] = *(const float4*)&As[kk][tm];
            *(float4*)&a[4] = *(const float4*)&As[kk][tm + 64];
            *(float4*)&b[0] = *(const float4*)&Bs[kk][tn];
            *(float4*)&b[4] = *(const float4*)&Bs[kk][tn + 64];
#pragma unroll
            for (int i = 0; i < 8; ++i)
#pragma unroll
                for (int j = 0; j < 8; ++j)
                    acc[i][j] = fmaf(a[i], b[j], acc[i][j]);
        }
    }
#pragma unroll
    for (int ih = 0; ih < 2; ++ih)
#pragma unroll
        for (int i = 0; i < 4; ++i) {
            size_t r = row0 + tm + ih * 64 + i;
            float* cp = Cc + r * (size_t)ldc + col0;
#pragma unroll
            for (int jh = 0; jh < 2; ++jh) {
                int cc = tn + jh * 64;
                float4 o;
                o.x = acc[ih * 4 + i][jh * 4 + 0];
                o.y = acc[ih * 4 + i][jh * 4 + 1];
                o.z = acc[ih * 4 + i][jh * 4 + 2];
                o.w = acc[ih * 4 + i][jh * 4 + 3];
                if (BIAS) {
                    const float* bp = bias + col0 + cc;
                    o.x += bp[0]; o.y += bp[1]; o.z += bp[2]; o.w += bp[3];
                }
                *(float4*)(cp + cc) = o;
            }
        }
}

__global__ __launch_bounds__(256) void center3_k(const float* __restrict__ Y,
                                                 const int* __restrict__ cluster,
                                                 const int* __restrict__ counts,
                                                 float* __restrict__ kc,
                                                 float* __restrict__ vc) {
    __shared__ int cl[NN];
    const int bb = blockIdx.x >> 8;
    const int c = blockIdx.x & (NCL - 1);
    const int tid = threadIdx.x;
    for (int i = tid; i < NN; i += 256) cl[i] = cluster[bb * NN + i];
    __syncthreads();
    float ka[4] = {0.f, 0.f, 0.f, 0.f};
    float va[4] = {0.f, 0.f, 0.f, 0.f};
    for (int t = 0; t < NN; ++t) {
        if (cl[t] == c) {
            const float* yr = Y + ((size_t)bb * NN + t) * 3072;
#pragma unroll
            for (int j = 0; j < 4; ++j) {
                ka[j] += yr[1024 + tid + 256 * j];
                va[j] += yr[2048 + tid + 256 * j];
            }
        }
    }
    int cnt = counts[bb * NCL + c];
    float inv = cnt > 0 ? 1.f / (float)cnt : 0.f;
    size_t o = ((size_t)bb * NCL + c) * DD;
#pragma unroll
    for (int j = 0; j < 4; ++j) {
        kc[o + tid + 256 * j] = ka[j] * inv;
        vc[o + tid + 256 * j] = va[j] * inv;
    }
}

__global__ __launch_bounds__(256) void attn3_k(float* __restrict__ Y,
                                               const float* __restrict__ kc,
                                               const float* __restrict__ vc,
                                               const int* __restrict__ counts) {
    const int ntile = blockIdx.x, hh = blockIdx.y, bb = blockIdx.z;
    const int tid = threadIdx.x;
    const int r = ntile * 256 + tid;
    float* yrow = Y + ((size_t)bb * NN + r) * 3072 + hh * DH;
    float q[DH];
#pragma unroll
    for (int e = 0; e < DH; e += 4) *(float4*)&q[e] = *(const float4*)(yrow + e);
    float acc[DH];
#pragma unroll
    for (int e = 0; e < DH; ++e) acc[e] = 0.f;
    float l = 0.f;
    const float* kcb = kc + ((size_t)bb * NCL) * DD + hh * DH;
    const float* vcb = vc + ((size_t)bb * NCL) * DD + hh * DH;
    const int* cnt = counts + bb * NCL;
    for (int c = 0; c < NCL; ++c) {
        const float* kr = kcb + (size_t)c * DD;
        float s0 = 0.f, s1 = 0.f, s2 = 0.f, s3 = 0.f;
#pragma unroll
        for (int e = 0; e < DH; e += 4) {
            s0 = fmaf(q[e + 0], kr[e + 0], s0);
            s1 = fmaf(q[e + 1], kr[e + 1], s1);
            s2 = fmaf(q[e + 2], kr[e + 2], s2);
            s3 = fmaf(q[e + 3], kr[e + 3], s3);
        }
        float s = ((s0 + s1) + (s2 + s3)) * 0.125f;
        float p = (float)cnt[c] * __expf(s);
        l += p;
        const float* vr = vcb + (size_t)c * DD;
#pragma unroll
        for (int e = 0; e < DH; ++e) acc[e] = fmaf(p, vr[e], acc[e]);
    }
    float invl = 1.f / l;
#pragma unroll
    for (int e = 0; e < DH; e += 4) {
        float4 o;
        o.x = acc[e + 0] * invl; o.y = acc[e + 1] * invl;
        o.z = acc[e + 2] * invl; o.w = acc[e + 3] * invl;
        *(float4*)(yrow + e) = o;
    }
}

// ---------------- launcher -------------------------------------------------
extern "C" void kernel_launch(void* const* d_in, const int* in_sizes, int n_in,
                              void* d_out, int out_size, void* d_ws, size_t ws_size,
                              hipStream_t stream) {
    const int* cluster  = (const int*)d_in[0];
    const float* x      = (const float*)d_in[1];
    const float* w_q    = (const float*)d_in[2];
    const float* w_kv   = (const float*)d_in[3];
    const float* w_proj = (const float*)d_in[4];
    const float* b_proj = (const float*)d_in[5];
    float* out = (float*)d_out;

    const size_t SZ_YKV = (size_t)MM * 2048 * 4;   // 256 MiB
    const size_t SZ_H   = (size_t)MM * 1024 * 2;   // 64 MiB per hi/lo buffer
    const size_t SZ_W   = (size_t)4096 * 1024 * 2; // 8 MiB per hi/lo
    const size_t SZ_C   = (size_t)BB * NCL * DD * 4;
    const size_t need = SZ_YKV + 4 * SZ_H + 2 * SZ_W + 2 * SZ_C + 65536;

    if (ws_size >= need) {
        char* p = (char*)d_ws;
        float* Ykv = (float*)p;        p += SZ_YKV;
        u16* Qhi = (u16*)p;            p += SZ_H;
        u16* Qlo = (u16*)p;            p += SZ_H;
        u16* Xhi = (u16*)p;            p += SZ_H;   // aliased as Phi after kv GEMM
        u16* Xlo = (u16*)p;            p += SZ_H;   // aliased as Plo
        u16* Wthi = (u16*)p;           p += SZ_W;
        u16* Wtlo = (u16*)p;           p += SZ_W;
        float* kc = (float*)p;         p += SZ_C;
        float* vc = (float*)p;         p += SZ_C;
        int* counts = (int*)p;

        hipMemsetAsync(counts, 0, BB * NCL * sizeof(int), stream);
        count_k<<<MM / 256, 256, 0, stream>>>(cluster, counts);
        convx_k<<<(size_t)MM * KK / 1024, 256, 0, stream>>>(x, Xhi, Xlo);
        convw_k<<<dim3(32, 32), 256, 0, stream>>>(w_q, 1024, Wthi, Wtlo);
        convw_k<<<dim3(64, 32), 256, 0, stream>>>(w_kv, 2048, Wthi + (size_t)1024 * KK, Wtlo + (size_t)1024 * KK);
        convw_k<<<dim3(32, 32), 256, 0, stream>>>(w_proj, 1024, Wthi + (size_t)3072 * KK, Wtlo + (size_t)3072 * KK);

        hgemm_k<2><<<dim3(8, 256), 256, 0, stream>>>(Xhi, Xlo, Wthi, Wtlo,
                                                     nullptr, 0, nullptr, Qhi, Qlo);
        hgemm_k<0><<<dim3(16, 256), 256, 0, stream>>>(Xhi, Xlo,
                                                      Wthi + (size_t)1024 * KK, Wtlo + (size_t)1024 * KK,
                                                      Ykv, 2048, nullptr, nullptr, nullptr);
        center2_k<<<BB * NCL, 256, 0, stream>>>(Ykv, cluster, counts, kc, vc);
        attn_bf_k<<<dim3(NN / 256, HEADS, BB), 256, 0, stream>>>(Qhi, Qlo, kc, vc, counts, Xhi, Xlo);
        hgemm_k<1><<<dim3(8, 256), 256, 0, stream>>>(Xhi, Xlo,
                                                     Wthi + (size_t)3072 * KK, Wtlo + (size_t)3072 * KK,
                                                     out, 1024, b_proj, nullptr, nullptr);
    } else {
        // round-2 fp32 fallback (needs ~420 MiB)
        char* ws = (char*)d_ws;
        float* Y = (float*)ws;
        size_t ybytes = (size_t)MM * 3072 * sizeof(float);
        float* kc = (float*)(ws + ybytes);
        float* vc = kc + (size_t)BB * NCL * DD;
        int* counts = (int*)(vc + (size_t)BB * NCL * DD);

        hipMemsetAsync(counts, 0, BB * NCL * sizeof(int), stream);
        count_k<<<MM / 256, 256, 0, stream>>>(cluster, counts);
        dim3 gq(DD / 128, MM / 128);
        sgemm_k<0><<<gq, 256, 0, stream>>>(x, DD, w_q, DD, Y, 3072, nullptr, DD);
        dim3 gkv(2 * DD / 128, MM / 128);
        sgemm_k<0><<<gkv, 256, 0, stream>>>(x, DD, w_kv, 2 * DD, Y + DD, 3072, nullptr, DD);
        center3_k<<<BB * NCL, 256, 0, stream>>>(Y, cluster, counts, kc, vc);
        attn3_k<<<dim3(NN / 256, HEADS, BB), 256, 0, stream>>>(Y, kc, vc, counts);
        dim3 gp(DD / 128, MM / 128);
        sgemm_k<1><<<gp, 256, 0, stream>>>(Y, 3072, w_proj, DD, out, DD, b_proj, DD);
    }
}

// Round 4
// 2130.424 us; speedup vs baseline: 2.3467x; 1.7931x over previous
//
#include <hip/hip_runtime.h>
#include <hip/hip_bf16.h>
#include <math.h>

#define HEADS 16
#define NCL 256
#define BB 8
#define NN 4096
#define DD 1024
#define DH 64
#define MM (BB*NN)   // 32768
#define KK 1024

typedef unsigned short u16;
typedef __attribute__((ext_vector_type(8))) short s8v;     // 8 bf16 (4 VGPRs)
typedef __attribute__((ext_vector_type(4))) float f32x4;   // MFMA C/D

__device__ __forceinline__ float bf2f(u16 u) {
    union { unsigned int i; float f; } v; v.i = ((unsigned int)u) << 16; return v.f;
}
__device__ __forceinline__ u16 f2bf(float x) {   // round-to-nearest-even
    union { float f; unsigned int i; } v; v.f = x;
    unsigned int u = v.i;
    return (u16)((u + 0x7FFFu + ((u >> 16) & 1u)) >> 16);
}
__device__ __forceinline__ void gl16(const u16* g, u16* l) {
    __builtin_amdgcn_global_load_lds(
        (__attribute__((address_space(1))) void*)g,
        (__attribute__((address_space(3))) void*)l, 16, 0, 0);
}

// ---------------- cluster counts (int atomics = deterministic) -------------
__global__ __launch_bounds__(256) void count_k(const int* __restrict__ cluster,
                                               int* __restrict__ counts) {
    int i = blockIdx.x * 256 + threadIdx.x;
    if (i < BB * NN) {
        int b = i / NN;
        atomicAdd(counts + b * NCL + cluster[i], 1);
    }
}

// ---------------- x -> bf16 hi/lo split ------------------------------------
__global__ __launch_bounds__(256) void convx_k(const float* __restrict__ x,
                                               u16* __restrict__ hi,
                                               u16* __restrict__ lo) {
    size_t i = ((size_t)blockIdx.x * 256 + threadIdx.x) * 4;
    float4 v = *(const float4*)(x + i);
    ushort4 h, l;
    h.x = f2bf(v.x); l.x = f2bf(v.x - bf2f(h.x));
    h.y = f2bf(v.y); l.y = f2bf(v.y - bf2f(h.y));
    h.z = f2bf(v.z); l.z = f2bf(v.z - bf2f(h.z));
    h.w = f2bf(v.w); l.w = f2bf(v.w - bf2f(h.w));
    *(ushort4*)(hi + i) = h;
    *(ushort4*)(lo + i) = l;
}

// ---------------- weight: [K=1024][N] fp32 -> [N][K] bf16 hi/lo ------------
__global__ __launch_bounds__(256) void convw_k(const float* __restrict__ w, int N,
                                               u16* __restrict__ thi,
                                               u16* __restrict__ tlo) {
    __shared__ float t[32][33];
    const int bx = blockIdx.x, by = blockIdx.y;
    const int lx = threadIdx.x & 31, ly = threadIdx.x >> 5;   // ly 0..7
#pragma unroll
    for (int p = 0; p < 4; ++p)
        t[p * 8 + ly][lx] = w[(size_t)(by * 32 + p * 8 + ly) * N + bx * 32 + lx];
    __syncthreads();
#pragma unroll
    for (int p = 0; p < 4; ++p) {
        int n = bx * 32 + p * 8 + ly;
        int k = by * 32 + lx;
        float v = t[lx][p * 8 + ly];
        u16 h = f2bf(v);
        thi[(size_t)n * KK + k] = h;
        tlo[(size_t)n * KK + k] = f2bf(v - bf2f(h));
    }
}

// ---------------- segment-sum of x over clusters -> bf16 hi/lo -------------
// one block per (b,c); fixed token order -> deterministic fp32 sums.
// xsum[b*256+c][:] = sum_{t: cluster[b,t]==c} x[b,t,:]   (0 if empty)
__global__ __launch_bounds__(256) void xsum_k(const float* __restrict__ x,
                                              const int* __restrict__ cluster,
                                              u16* __restrict__ shi,
                                              u16* __restrict__ slo) {
    __shared__ int cl[NN];   // 16 KB
    const int bb = blockIdx.x >> 8;
    const int c = blockIdx.x & (NCL - 1);
    const int tid = threadIdx.x;

    for (int i = tid; i < NN; i += 256) cl[i] = cluster[bb * NN + i];
    __syncthreads();

    float a[4] = {0.f, 0.f, 0.f, 0.f};
    for (int t = 0; t < NN; ++t) {
        if (cl[t] == c) {
            const float* xr = x + ((size_t)bb * NN + t) * DD;
#pragma unroll
            for (int j = 0; j < 4; ++j) a[j] += xr[tid + 256 * j];
        }
    }
    size_t o = ((size_t)bb * NCL + c) * DD;
#pragma unroll
    for (int j = 0; j < 4; ++j) {
        u16 h = f2bf(a[j]);
        shi[o + tid + 256 * j] = h;
        slo[o + tid + 256 * j] = f2bf(a[j] - bf2f(h));
    }
}

// ---------------- split-bf16 MFMA GEMM -------------------------------------
// C = A@B via (Ahi+Alo)@(Bhi+Blo), dropping lo*lo (~2^-18 rel).
// A: [M][K] bf16 hi/lo, B: [N][K] bf16 hi/lo (pre-transposed weights).
// 128x128 tile, BK=32, 4 waves (2x2), 4x4 16x16x32 frags/wave, 48 MFMA/K-step.
// Staging: global_load_lds 16B, linear LDS dest; conflict-free ds_read via
// quarter-XOR swizzle applied on the per-lane GLOBAL source address and the
// same involution on the read side (guide rule 21).
// OUT: 0 = f32 C, 1 = f32 C + bias, 2 = bf16 hi/lo split (ld 1024)
template<int OUT>
__global__ __launch_bounds__(256) void hgemm_k(
        const u16* __restrict__ Ahi, const u16* __restrict__ Alo,
        const u16* __restrict__ Bhi, const u16* __restrict__ Blo,
        float* __restrict__ C, int ldc, const float* __restrict__ bias,
        u16* __restrict__ Ohi, u16* __restrict__ Olo) {
    __shared__ u16 sh[4][128 * 32];   // Ahi | Alo | Bhi | Blo, 8 KB each

    const int tid = threadIdx.x;
    const int lane = tid & 63;
    const int wid = tid >> 6;
    const int wm = wid >> 1, wn = wid & 1;
    const size_t row0 = (size_t)blockIdx.y * 128;
    const size_t col0 = (size_t)blockIdx.x * 128;

    // staging map: thread t -> rows (sr, sr+64), 16B quarter sq; source quarter
    // swizzled by row: qs = sq ^ ((sr>>1)&3). ((sr+64)>>1)&3 == ((sr>>1)&3).
    const int sr = tid >> 2;
    const int sq = tid & 3;
    const int qs = sq ^ ((sr >> 1) & 3);

    const u16* ga0 = Ahi + (row0 + sr) * KK + qs * 8;
    const u16* ga1 = ga0 + (size_t)64 * KK;
    const u16* gA0 = Alo + (row0 + sr) * KK + qs * 8;
    const u16* gA1 = gA0 + (size_t)64 * KK;
    const u16* gb0 = Bhi + (col0 + sr) * KK + qs * 8;
    const u16* gb1 = gb0 + (size_t)64 * KK;
    const u16* gB0 = Blo + (col0 + sr) * KK + qs * 8;
    const u16* gB1 = gB0 + (size_t)64 * KK;

    u16* d = (u16*)sh + tid * 8;   // linear dest (lane-ordered); halves +2048

    // read offsets: lane reads row rX, global k-quarter lane>>4 -> swizzled
    // slot. Swizzle bits invariant under row += 16*i (frag index).
    const int rA = wm * 64 + (lane & 15);
    const int rB = wn * 64 + (lane & 15);
    const int aoff = rA * 32 + (((lane >> 4) ^ ((rA >> 1) & 3)) * 8);
    const int boff = rB * 32 + (((lane >> 4) ^ ((rB >> 1) & 3)) * 8);

    f32x4 acc[4][4] = {};

    for (int k0 = 0; k0 < KK; k0 += 32) {
        gl16(ga0 + k0, d);
        gl16(ga1 + k0, d + 2048);
        gl16(gA0 + k0, d + 4096);
        gl16(gA1 + k0, d + 6144);
        gl16(gb0 + k0, d + 8192);
        gl16(gb1 + k0, d + 10240);
        gl16(gB0 + k0, d + 12288);
        gl16(gB1 + k0, d + 14336);
        __syncthreads();   // compiler drains vmcnt(0) before s_barrier
        s8v ah[4], al[4], bh[4], bl[4];
#pragma unroll
        for (int i = 0; i < 4; ++i) {
            ah[i] = *(const s8v*)&sh[0][aoff + i * 512];
            al[i] = *(const s8v*)&sh[1][aoff + i * 512];
            bh[i] = *(const s8v*)&sh[2][boff + i * 512];
            bl[i] = *(const s8v*)&sh[3][boff + i * 512];
        }
#pragma unroll
        for (int i = 0; i < 4; ++i)
#pragma unroll
            for (int j = 0; j < 4; ++j) {
                acc[i][j] = __builtin_amdgcn_mfma_f32_16x16x32_bf16(ah[i], bh[j], acc[i][j], 0, 0, 0);
                acc[i][j] = __builtin_amdgcn_mfma_f32_16x16x32_bf16(ah[i], bl[j], acc[i][j], 0, 0, 0);
                acc[i][j] = __builtin_amdgcn_mfma_f32_16x16x32_bf16(al[i], bh[j], acc[i][j], 0, 0, 0);
            }
        __syncthreads();   // reads done before next stage overwrites
    }

    const int fr = (lane >> 4) * 4;   // C/D: row = (lane>>4)*4 + reg
    const int fc = lane & 15;         //      col = lane & 15

    if constexpr (OUT == 2) {
#pragma unroll
        for (int i = 0; i < 4; ++i)
#pragma unroll
            for (int j = 0; j < 4; ++j) {
                size_t rbase = row0 + wm * 64 + i * 16 + fr;
                size_t cidx = col0 + wn * 64 + j * 16 + fc;
#pragma unroll
                for (int g = 0; g < 4; ++g) {
                    float o = acc[i][j][g];
                    u16 h = f2bf(o);
                    u16 l2 = f2bf(o - bf2f(h));
                    size_t idx = (rbase + g) * 1024 + cidx;
                    Ohi[idx] = h;
                    Olo[idx] = l2;
                }
            }
    } else {
        float bj[4] = {0.f, 0.f, 0.f, 0.f};
        if constexpr (OUT == 1) {
#pragma unroll
            for (int j = 0; j < 4; ++j) bj[j] = bias[col0 + wn * 64 + j * 16 + fc];
        }
#pragma unroll
        for (int i = 0; i < 4; ++i)
#pragma unroll
            for (int j = 0; j < 4; ++j) {
                size_t rbase = row0 + wm * 64 + i * 16 + fr;
                size_t cidx = col0 + wn * 64 + j * 16 + fc;
#pragma unroll
                for (int g = 0; g < 4; ++g)
                    C[(rbase + g) * (size_t)ldc + cidx] = acc[i][j][g] + bj[j];
            }
    }
}

// ---------------- attention over cluster centers ---------------------------
// Csum row (b*256+c): [0:1024) = ksum, [1024:2048) = vsum (un-normalized).
// s_c = (q . ksum_c) * inv_c / 8;  ex = exp(s_c);
// l += cnt_c * ex;  acc += ex * vsum_c   (empty cluster: vsum=0, cnt=0 -> 0)
// out = acc / l. In: q bf16 hi/lo. Out: bf16 hi/lo (for proj GEMM).
__global__ __launch_bounds__(256) void attn_bf_k(const u16* __restrict__ Qhi,
                                                 const u16* __restrict__ Qlo,
                                                 const float* __restrict__ Csum,
                                                 const int* __restrict__ counts,
                                                 u16* __restrict__ Phi,
                                                 u16* __restrict__ Plo) {
    const int ntile = blockIdx.x, hh = blockIdx.y, bb = blockIdx.z;
    const int tid = threadIdx.x;
    const int r = ntile * 256 + tid;
    const size_t qoff = ((size_t)bb * NN + r) * 1024 + hh * DH;

    float q[DH];
#pragma unroll
    for (int e = 0; e < DH; e += 4) {
        ushort4 h4 = *(const ushort4*)(Qhi + qoff + e);
        ushort4 l4 = *(const ushort4*)(Qlo + qoff + e);
        q[e + 0] = bf2f(h4.x) + bf2f(l4.x);
        q[e + 1] = bf2f(h4.y) + bf2f(l4.y);
        q[e + 2] = bf2f(h4.z) + bf2f(l4.z);
        q[e + 3] = bf2f(h4.w) + bf2f(l4.w);
    }

    float acc[DH];
#pragma unroll
    for (int e = 0; e < DH; ++e) acc[e] = 0.f;
    float l = 0.f;

    const float* cb = Csum + ((size_t)bb * NCL) * 2048 + hh * DH;
    const int* cnt = counts + bb * NCL;

    for (int c = 0; c < NCL; ++c) {
        const float* kr = cb + (size_t)c * 2048;        // block-uniform -> s_load
        const float* vr = kr + 1024;
        int n = cnt[c];
        float inv = n > 0 ? 1.f / (float)n : 0.f;
        float s0 = 0.f, s1 = 0.f, s2 = 0.f, s3 = 0.f;
#pragma unroll
        for (int e = 0; e < DH; e += 4) {
            s0 = fmaf(q[e + 0], kr[e + 0], s0);
            s1 = fmaf(q[e + 1], kr[e + 1], s1);
            s2 = fmaf(q[e + 2], kr[e + 2], s2);
            s3 = fmaf(q[e + 3], kr[e + 3], s3);
        }
        float s = ((s0 + s1) + (s2 + s3)) * 0.125f * inv;
        float ex = __expf(s);
        l += (float)n * ex;
#pragma unroll
        for (int e = 0; e < DH; ++e) acc[e] = fmaf(ex, vr[e], acc[e]);
    }

    float invl = 1.f / l;
#pragma unroll
    for (int e = 0; e < DH; e += 4) {
        ushort4 h4, l4;
        float o0 = acc[e + 0] * invl, o1 = acc[e + 1] * invl;
        float o2 = acc[e + 2] * invl, o3 = acc[e + 3] * invl;
        h4.x = f2bf(o0); l4.x = f2bf(o0 - bf2f(h4.x));
        h4.y = f2bf(o1); l4.y = f2bf(o1 - bf2f(h4.y));
        h4.z = f2bf(o2); l4.z = f2bf(o2 - bf2f(h4.z));
        h4.w = f2bf(o3); l4.w = f2bf(o3 - bf2f(h4.w));
        *(ushort4*)(Phi + qoff + e) = h4;
        *(ushort4*)(Plo + qoff + e) = l4;
    }
}

// ---------------- launcher -------------------------------------------------
extern "C" void kernel_launch(void* const* d_in, const int* in_sizes, int n_in,
                              void* d_out, int out_size, void* d_ws, size_t ws_size,
                              hipStream_t stream) {
    const int* cluster  = (const int*)d_in[0];
    const float* x      = (const float*)d_in[1];
    const float* w_q    = (const float*)d_in[2];
    const float* w_kv   = (const float*)d_in[3];
    const float* w_proj = (const float*)d_in[4];
    const float* b_proj = (const float*)d_in[5];
    float* out = (float*)d_out;

    // layout (~296 MiB):
    //   Xhi/Xlo   [32768][1024] u16   64 MiB x2   (reused as Phi/Plo)
    //   Qhi/Qlo   [32768][1024] u16   64 MiB x2
    //   Wthi/Wtlo [4096][1024]  u16    8 MiB x2   (wq | wkv | wproj, transposed)
    //   XShi/XSlo [2048][1024]  u16    4 MiB x2   (cluster sums of x)
    //   Csum      [2048][2048]  f32   16 MiB      (ksum | vsum per (b,c))
    //   counts    [8][256]      i32
    const size_t SZ_H  = (size_t)MM * 1024 * 2;
    const size_t SZ_W  = (size_t)4096 * 1024 * 2;
    const size_t SZ_XS = (size_t)2048 * 1024 * 2;
    const size_t SZ_CS = (size_t)2048 * 2048 * 4;

    char* p = (char*)d_ws;
    u16* Xhi = (u16*)p;   p += SZ_H;
    u16* Xlo = (u16*)p;   p += SZ_H;
    u16* Qhi = (u16*)p;   p += SZ_H;
    u16* Qlo = (u16*)p;   p += SZ_H;
    u16* Wthi = (u16*)p;  p += SZ_W;
    u16* Wtlo = (u16*)p;  p += SZ_W;
    u16* XShi = (u16*)p;  p += SZ_XS;
    u16* XSlo = (u16*)p;  p += SZ_XS;
    float* Csum = (float*)p; p += SZ_CS;
    int* counts = (int*)p;

    hipMemsetAsync(counts, 0, BB * NCL * sizeof(int), stream);
    count_k<<<MM / 256, 256, 0, stream>>>(cluster, counts);

    convx_k<<<(size_t)MM * KK / 1024, 256, 0, stream>>>(x, Xhi, Xlo);
    convw_k<<<dim3(32, 32), 256, 0, stream>>>(w_q, 1024, Wthi, Wtlo);
    convw_k<<<dim3(64, 32), 256, 0, stream>>>(w_kv, 2048, Wthi + (size_t)1024 * KK, Wtlo + (size_t)1024 * KK);
    convw_k<<<dim3(32, 32), 256, 0, stream>>>(w_proj, 1024, Wthi + (size_t)3072 * KK, Wtlo + (size_t)3072 * KK);

    xsum_k<<<BB * NCL, 256, 0, stream>>>(x, cluster, XShi, XSlo);

    // Q = X @ Wq^T  -> bf16 hi/lo
    hgemm_k<2><<<dim3(8, 256), 256, 0, stream>>>(Xhi, Xlo, Wthi, Wtlo,
                                                 nullptr, 0, nullptr, Qhi, Qlo);
    // Csum = XS @ Wkv^T (ksum | vsum), fp32
    hgemm_k<0><<<dim3(16, 16), 256, 0, stream>>>(XShi, XSlo,
                                                 Wthi + (size_t)1024 * KK, Wtlo + (size_t)1024 * KK,
                                                 Csum, 2048, nullptr, nullptr, nullptr);
    // attention -> P (bf16 hi/lo, aliases X buffers)
    attn_bf_k<<<dim3(NN / 256, HEADS, BB), 256, 0, stream>>>(Qhi, Qlo, Csum, counts, Xhi, Xlo);
    // out = P @ Wproj^T + bias
    hgemm_k<1><<<dim3(8, 256), 256, 0, stream>>>(Xhi, Xlo,
                                                 Wthi + (size_t)3072 * KK, Wtlo + (size_t)3072 * KK,
                                                 out, 1024, b_proj, nullptr, nullptr);
}

// Round 6
// 1012.834 us; speedup vs baseline: 4.9361x; 2.1034x over previous
//
#include <hip/hip_runtime.h>
#include <hip/hip_bf16.h>
#include <math.h>

#define HEADS 16
#define NCL 256
#define BB 8
#define NN 4096
#define DD 1024
#define DH 64
#define MM (BB*NN)   // 32768
#define KK 1024

typedef unsigned short u16;
typedef __attribute__((ext_vector_type(8))) short s8v;     // 8 bf16 (4 VGPRs)
typedef __attribute__((ext_vector_type(4))) float f32x4;   // MFMA C/D

__device__ __forceinline__ float bf2f(u16 u) {
    union { unsigned int i; float f; } v; v.i = ((unsigned int)u) << 16; return v.f;
}
__device__ __forceinline__ u16 f2bf(float x) {   // round-to-nearest-even
    union { float f; unsigned int i; } v; v.f = x;
    unsigned int u = v.i;
    return (u16)((u + 0x7FFFu + ((u >> 16) & 1u)) >> 16);
}
__device__ __forceinline__ void gl16(const u16* g, u16* l) {
    __builtin_amdgcn_global_load_lds(
        (__attribute__((address_space(1))) void*)g,
        (__attribute__((address_space(3))) void*)l, 16, 0, 0);
}

// ---------------- cluster counts (int atomics = deterministic) -------------
__global__ __launch_bounds__(256) void count_k(const int* __restrict__ cluster,
                                               int* __restrict__ counts) {
    int i = blockIdx.x * 256 + threadIdx.x;
    if (i < BB * NN) {
        int b = i / NN;
        atomicAdd(counts + b * NCL + cluster[i], 1);
    }
}

// ---------------- per-(b,c) table: (0.125/cnt, cnt) ------------------------
__global__ __launch_bounds__(256) void tab_k(const int* __restrict__ counts,
                                             float2* __restrict__ tab) {
    int i = blockIdx.x * 256 + threadIdx.x;   // b*256 + c
    int n = counts[i];
    float2 t;
    t.x = n > 0 ? 0.125f / (float)n : 0.f;
    t.y = (float)n;
    tab[i] = t;
}

// ---------------- x -> bf16 hi/lo split ------------------------------------
__global__ __launch_bounds__(256) void convx_k(const float* __restrict__ x,
                                               u16* __restrict__ hi,
                                               u16* __restrict__ lo) {
    size_t i = ((size_t)blockIdx.x * 256 + threadIdx.x) * 4;
    float4 v = *(const float4*)(x + i);
    ushort4 h, l;
    h.x = f2bf(v.x); l.x = f2bf(v.x - bf2f(h.x));
    h.y = f2bf(v.y); l.y = f2bf(v.y - bf2f(h.y));
    h.z = f2bf(v.z); l.z = f2bf(v.z - bf2f(h.z));
    h.w = f2bf(v.w); l.w = f2bf(v.w - bf2f(h.w));
    *(ushort4*)(hi + i) = h;
    *(ushort4*)(lo + i) = l;
}

// ---------------- weight: [K=1024][N] fp32 -> [N][K] bf16 hi/lo ------------
__global__ __launch_bounds__(256) void convw_k(const float* __restrict__ w, int N,
                                               u16* __restrict__ thi,
                                               u16* __restrict__ tlo) {
    __shared__ float t[32][33];
    const int bx = blockIdx.x, by = blockIdx.y;
    const int lx = threadIdx.x & 31, ly = threadIdx.x >> 5;   // ly 0..7
#pragma unroll
    for (int p = 0; p < 4; ++p)
        t[p * 8 + ly][lx] = w[(size_t)(by * 32 + p * 8 + ly) * N + bx * 32 + lx];
    __syncthreads();
#pragma unroll
    for (int p = 0; p < 4; ++p) {
        int n = bx * 32 + p * 8 + ly;
        int k = by * 32 + lx;
        float v = t[lx][p * 8 + ly];
        u16 h = f2bf(v);
        thi[(size_t)n * KK + k] = h;
        tlo[(size_t)n * KK + k] = f2bf(v - bf2f(h));
    }
}

// ---------------- segment-sum of x over clusters -> bf16 hi/lo -------------
__global__ __launch_bounds__(256) void xsum_k(const float* __restrict__ x,
                                              const int* __restrict__ cluster,
                                              u16* __restrict__ shi,
                                              u16* __restrict__ slo) {
    __shared__ int cl[NN];   // 16 KB
    const int bb = blockIdx.x >> 8;
    const int c = blockIdx.x & (NCL - 1);
    const int tid = threadIdx.x;

    for (int i = tid; i < NN; i += 256) cl[i] = cluster[bb * NN + i];
    __syncthreads();

    float a[4] = {0.f, 0.f, 0.f, 0.f};
    for (int t = 0; t < NN; ++t) {
        if (cl[t] == c) {
            const float* xr = x + ((size_t)bb * NN + t) * DD;
#pragma unroll
            for (int j = 0; j < 4; ++j) a[j] += xr[tid + 256 * j];
        }
    }
    size_t o = ((size_t)bb * NCL + c) * DD;
#pragma unroll
    for (int j = 0; j < 4; ++j) {
        u16 h = f2bf(a[j]);
        shi[o + tid + 256 * j] = h;
        slo[o + tid + 256 * j] = f2bf(a[j] - bf2f(h));
    }
}

// ---------------- Csum k-part -> K [b][h][256 cl][64] bf16 hi/lo, swizzled -
// 16B-unit u within each 128B row stored at u ^ (cl&7).
__global__ __launch_bounds__(256) void convk_k(const float* __restrict__ Csum,
                                               u16* __restrict__ khi,
                                               u16* __restrict__ klo) {
    const int bh = blockIdx.x;            // b*16 + h
    const int bb = bh >> 4, hh = bh & 15;
    const int tid = threadIdx.x;
#pragma unroll
    for (int i = 0; i < 8; ++i) {
        int ulin = tid + 256 * i;          // cl*8 + u
        int c = ulin >> 3, u = ulin & 7;
        const float* src = Csum + ((size_t)(bb * NCL + c)) * 2048 + hh * 64 + u * 8;
        float4 v0 = *(const float4*)src;
        float4 v1 = *(const float4*)(src + 4);
        size_t o = ((size_t)bh * NCL + c) * 64 + ((u ^ (c & 7)) << 3);
        ushort4 h0, l0, h1, l1;
        h0.x = f2bf(v0.x); l0.x = f2bf(v0.x - bf2f(h0.x));
        h0.y = f2bf(v0.y); l0.y = f2bf(v0.y - bf2f(h0.y));
        h0.z = f2bf(v0.z); l0.z = f2bf(v0.z - bf2f(h0.z));
        h0.w = f2bf(v0.w); l0.w = f2bf(v0.w - bf2f(h0.w));
        h1.x = f2bf(v1.x); l1.x = f2bf(v1.x - bf2f(h1.x));
        h1.y = f2bf(v1.y); l1.y = f2bf(v1.y - bf2f(h1.y));
        h1.z = f2bf(v1.z); l1.z = f2bf(v1.z - bf2f(h1.z));
        h1.w = f2bf(v1.w); l1.w = f2bf(v1.w - bf2f(h1.w));
        *(ushort4*)(khi + o) = h0; *(ushort4*)(khi + o + 4) = h1;
        *(ushort4*)(klo + o) = l0; *(ushort4*)(klo + o + 4) = l1;
    }
}

// ---------------- Csum v-part -> V^T [b][h][64 d][256 cl] hi/lo, swizzled --
// 16B-unit u within each 512B row stored at (u&24)|((u^d)&7).
__global__ __launch_bounds__(256) void convv_k(const float* __restrict__ Csum,
                                               u16* __restrict__ vthi,
                                               u16* __restrict__ vtlo) {
    __shared__ float vb[NCL][65];   // 66.5 KB
    const int bh = blockIdx.x;
    const int bb = bh >> 4, hh = bh & 15;
    const int tid = threadIdx.x;
    const int d0 = tid & 63;
#pragma unroll
    for (int i = 0; i < 64; ++i) {
        int c = (tid >> 6) + i * 4;
        vb[c][d0] = Csum[((size_t)(bb * NCL + c)) * 2048 + 1024 + hh * 64 + d0];
    }
    __syncthreads();
    const int d = tid >> 2;
    const int uq = tid & 3;
#pragma unroll
    for (int j = 0; j < 8; ++j) {
        int u = uq * 8 + j;                // original unit (8 clusters)
        int c0 = u * 8;
        float v[8];
#pragma unroll
        for (int e = 0; e < 8; ++e) v[e] = vb[c0 + e][d];
        ushort4 h0, l0, h1, l1;
        h0.x = f2bf(v[0]); l0.x = f2bf(v[0] - bf2f(h0.x));
        h0.y = f2bf(v[1]); l0.y = f2bf(v[1] - bf2f(h0.y));
        h0.z = f2bf(v[2]); l0.z = f2bf(v[2] - bf2f(h0.z));
        h0.w = f2bf(v[3]); l0.w = f2bf(v[3] - bf2f(h0.w));
        h1.x = f2bf(v[4]); l1.x = f2bf(v[4] - bf2f(h1.x));
        h1.y = f2bf(v[5]); l1.y = f2bf(v[5] - bf2f(h1.y));
        h1.z = f2bf(v[6]); l1.z = f2bf(v[6] - bf2f(h1.z));
        h1.w = f2bf(v[7]); l1.w = f2bf(v[7] - bf2f(h1.w));
        int usw = (u & 24) | ((u ^ d) & 7);  // low3 bits XOR'd within 8-group
        size_t o = ((size_t)bh * 64 + d) * 256 + usw * 8;
        *(ushort4*)(vthi + o) = h0; *(ushort4*)(vthi + o + 4) = h1;
        *(ushort4*)(vtlo + o) = l0; *(ushort4*)(vtlo + o + 4) = l1;
    }
}

// ---------------- split-bf16 MFMA GEMM (unchanged, proven) -----------------
template<int OUT>
__global__ __launch_bounds__(256) void hgemm_k(
        const u16* __restrict__ Ahi, const u16* __restrict__ Alo,
        const u16* __restrict__ Bhi, const u16* __restrict__ Blo,
        float* __restrict__ C, int ldc, const float* __restrict__ bias,
        u16* __restrict__ Ohi, u16* __restrict__ Olo) {
    __shared__ u16 sh[4][128 * 32];

    const int tid = threadIdx.x;
    const int lane = tid & 63;
    const int wid = tid >> 6;
    const int wm = wid >> 1, wn = wid & 1;
    const size_t row0 = (size_t)blockIdx.y * 128;
    const size_t col0 = (size_t)blockIdx.x * 128;

    const int sr = tid >> 2;
    const int sq = tid & 3;
    const int qs = sq ^ ((sr >> 1) & 3);

    const u16* ga0 = Ahi + (row0 + sr) * KK + qs * 8;
    const u16* ga1 = ga0 + (size_t)64 * KK;
    const u16* gA0 = Alo + (row0 + sr) * KK + qs * 8;
    const u16* gA1 = gA0 + (size_t)64 * KK;
    const u16* gb0 = Bhi + (col0 + sr) * KK + qs * 8;
    const u16* gb1 = gb0 + (size_t)64 * KK;
    const u16* gB0 = Blo + (col0 + sr) * KK + qs * 8;
    const u16* gB1 = gB0 + (size_t)64 * KK;

    u16* d = (u16*)sh + tid * 8;

    const int rA = wm * 64 + (lane & 15);
    const int rB = wn * 64 + (lane & 15);
    const int aoff = rA * 32 + (((lane >> 4) ^ ((rA >> 1) & 3)) * 8);
    const int boff = rB * 32 + (((lane >> 4) ^ ((rB >> 1) & 3)) * 8);

    f32x4 acc[4][4] = {};

    for (int k0 = 0; k0 < KK; k0 += 32) {
        gl16(ga0 + k0, d);
        gl16(ga1 + k0, d + 2048);
        gl16(gA0 + k0, d + 4096);
        gl16(gA1 + k0, d + 6144);
        gl16(gb0 + k0, d + 8192);
        gl16(gb1 + k0, d + 10240);
        gl16(gB0 + k0, d + 12288);
        gl16(gB1 + k0, d + 14336);
        __syncthreads();
        s8v ah[4], al[4], bh[4], bl[4];
#pragma unroll
        for (int i = 0; i < 4; ++i) {
            ah[i] = *(const s8v*)&sh[0][aoff + i * 512];
            al[i] = *(const s8v*)&sh[1][aoff + i * 512];
            bh[i] = *(const s8v*)&sh[2][boff + i * 512];
            bl[i] = *(const s8v*)&sh[3][boff + i * 512];
        }
#pragma unroll
        for (int i = 0; i < 4; ++i)
#pragma unroll
            for (int j = 0; j < 4; ++j) {
                acc[i][j] = __builtin_amdgcn_mfma_f32_16x16x32_bf16(ah[i], bh[j], acc[i][j], 0, 0, 0);
                acc[i][j] = __builtin_amdgcn_mfma_f32_16x16x32_bf16(ah[i], bl[j], acc[i][j], 0, 0, 0);
                acc[i][j] = __builtin_amdgcn_mfma_f32_16x16x32_bf16(al[i], bh[j], acc[i][j], 0, 0, 0);
            }
        __syncthreads();
    }

    const int fr = (lane >> 4) * 4;
    const int fc = lane & 15;

    if constexpr (OUT == 2) {
#pragma unroll
        for (int i = 0; i < 4; ++i)
#pragma unroll
            for (int j = 0; j < 4; ++j) {
                size_t rbase = row0 + wm * 64 + i * 16 + fr;
                size_t cidx = col0 + wn * 64 + j * 16 + fc;
#pragma unroll
                for (int g = 0; g < 4; ++g) {
                    float o = acc[i][j][g];
                    u16 h = f2bf(o);
                    u16 l2 = f2bf(o - bf2f(h));
                    size_t idx = (rbase + g) * 1024 + cidx;
                    Ohi[idx] = h;
                    Olo[idx] = l2;
                }
            }
    } else {
        float bj[4] = {0.f, 0.f, 0.f, 0.f};
        if constexpr (OUT == 1) {
#pragma unroll
            for (int j = 0; j < 4; ++j) bj[j] = bias[col0 + wn * 64 + j * 16 + fc];
        }
#pragma unroll
        for (int i = 0; i < 4; ++i)
#pragma unroll
            for (int j = 0; j < 4; ++j) {
                size_t rbase = row0 + wm * 64 + i * 16 + fr;
                size_t cidx = col0 + wn * 64 + j * 16 + fc;
#pragma unroll
                for (int g = 0; g < 4; ++g)
                    C[(rbase + g) * (size_t)ldc + cidx] = acc[i][j][g] + bj[j];
            }
    }
}

// ---------------- fused MFMA attention -------------------------------------
// Block = (b, h, 64 tokens), 4 waves. Wave w owns cluster slice w*64..+63.
// QK^T swapped: S^T = Ksum @ Q^T -> token in lane&15; softmax over clusters
// is lane-local + shfl_xor(16,32) + cross-wave LDS sum.
// z = exp(s*0.125/cnt)*[cnt>0] (bf16 hi/lo in LDS, XOR-swizzled);
// l = sum cnt*exp. PV: out^T = V^T @ z. Epilogue scales by 1/l.
__global__ __launch_bounds__(256) void fattn_k(const u16* __restrict__ Qhi,
                                               const u16* __restrict__ Qlo,
                                               const u16* __restrict__ Khi,
                                               const u16* __restrict__ Klo,
                                               const u16* __restrict__ Vthi,
                                               const u16* __restrict__ Vtlo,
                                               const float2* __restrict__ tab,
                                               u16* __restrict__ Phi,
                                               u16* __restrict__ Plo) {
    __shared__ u16 zh[64 * 256];     // 32 KB  [tokL][cl], 16B-unit ^ (tokL&7)
    __shared__ u16 zl[64 * 256];     // 32 KB
    __shared__ float lpart[4][64];
    __shared__ float invl[64];

    const int tid = threadIdx.x;
    const int lane = tid & 63;
    const int w = tid >> 6;
    const int g = lane >> 4;
    const int l15 = lane & 15;
    const int hh = blockIdx.y, bb = blockIdx.z;
    const int bh = bb * 16 + hh;
    const int tok0 = blockIdx.x * 64;

    // ---- Q^T B-frags (held in regs for the whole QK phase) ----
    s8v qf[2][4][2];   // [ks][cf][hi/lo]
#pragma unroll
    for (int cf = 0; cf < 4; ++cf)
#pragma unroll
        for (int ks = 0; ks < 2; ++ks) {
            size_t qo = ((size_t)(bb * NN + tok0 + cf * 16 + l15)) * 1024
                        + hh * 64 + ks * 32 + g * 8;
            qf[ks][cf][0] = *(const s8v*)(Qhi + qo);
            qf[ks][cf][1] = *(const s8v*)(Qlo + qo);
        }

    // ---- QK^T: acc[f][cf] = S^T[cl 16-slice][tok 16-slice] ----
    f32x4 acc[4][4] = {};
    const size_t kbase = (size_t)bh * NCL * 64;
#pragma unroll
    for (int f = 0; f < 4; ++f) {
        const int cl = w * 64 + f * 16 + l15;
        s8v kf[2][2];
#pragma unroll
        for (int ks = 0; ks < 2; ++ks) {
            size_t ko = kbase + (size_t)cl * 64 + (((ks * 4 + g) ^ (l15 & 7)) << 3);
            kf[ks][0] = *(const s8v*)(Khi + ko);
            kf[ks][1] = *(const s8v*)(Klo + ko);
        }
#pragma unroll
        for (int cf = 0; cf < 4; ++cf)
#pragma unroll
            for (int ks = 0; ks < 2; ++ks) {
                acc[f][cf] = __builtin_amdgcn_mfma_f32_16x16x32_bf16(kf[ks][0], qf[ks][cf][0], acc[f][cf], 0, 0, 0);
                acc[f][cf] = __builtin_amdgcn_mfma_f32_16x16x32_bf16(kf[ks][0], qf[ks][cf][1], acc[f][cf], 0, 0, 0);
                acc[f][cf] = __builtin_amdgcn_mfma_f32_16x16x32_bf16(kf[ks][1], qf[ks][cf][0], acc[f][cf], 0, 0, 0);
            }
    }

    // ---- softmax weights ----
    float lp[4] = {0.f, 0.f, 0.f, 0.f};
#pragma unroll
    for (int f = 0; f < 4; ++f) {
        float2 t4[4];
#pragma unroll
        for (int r = 0; r < 4; ++r)
            t4[r] = tab[bb * NCL + w * 64 + f * 16 + 4 * g + r];
#pragma unroll
        for (int cf = 0; cf < 4; ++cf) {
            float z[4];
#pragma unroll
            for (int r = 0; r < 4; ++r) {
                float e = __expf(acc[f][cf][r] * t4[r].x);
                lp[cf] += t4[r].y * e;
                z[r] = t4[r].y > 0.f ? e : 0.f;
            }
            const int tokL = cf * 16 + l15;
            // FIX (round 5 NaN): cluster index must include the wave's
            // w*64 slice offset — without it clusters 64..255 were never
            // written and PV read uninitialized LDS.
            int idx = (tokL * 256 + w * 64 + f * 16 + 4 * g) ^ (8 * (l15 & 7));
            uint2 ph, pl;
            u16 h0 = f2bf(z[0]), h1 = f2bf(z[1]), h2 = f2bf(z[2]), h3 = f2bf(z[3]);
            ph.x = (unsigned int)h0 | ((unsigned int)h1 << 16);
            ph.y = (unsigned int)h2 | ((unsigned int)h3 << 16);
            pl.x = (unsigned int)f2bf(z[0] - bf2f(h0)) | ((unsigned int)f2bf(z[1] - bf2f(h1)) << 16);
            pl.y = (unsigned int)f2bf(z[2] - bf2f(h2)) | ((unsigned int)f2bf(z[3] - bf2f(h3)) << 16);
            *(uint2*)&zh[idx] = ph;
            *(uint2*)&zl[idx] = pl;
        }
    }
#pragma unroll
    for (int cf = 0; cf < 4; ++cf) {
        lp[cf] += __shfl_xor(lp[cf], 16);
        lp[cf] += __shfl_xor(lp[cf], 32);
    }
    if (lane < 16) {
#pragma unroll
        for (int cf = 0; cf < 4; ++cf) lpart[w][cf * 16 + lane] = lp[cf];
    }
    __syncthreads();

    if (w == 0)
        invl[lane] = 1.f / (lpart[0][lane] + lpart[1][lane] + lpart[2][lane] + lpart[3][lane]);

    // ---- PV: out^T[d 16-slice][tok] ----
    f32x4 oacc[4] = {};
    const size_t vbase = (size_t)bh * 64 * 256;
    const int dg = w * 16 + l15;
#pragma unroll
    for (int ks = 0; ks < 8; ++ks) {
        size_t vo = vbase + (size_t)dg * 256
                    + (((ks * 4 + g) & 24) | (((ks * 4 + g) ^ dg) & 7)) * 8;
        s8v va = *(const s8v*)(Vthi + vo);
        s8v vb = *(const s8v*)(Vtlo + vo);
#pragma unroll
        for (int cf = 0; cf < 4; ++cf) {
            int idx = ((cf * 16 + l15) * 256 + ks * 32 + g * 8) ^ (8 * (l15 & 7));
            s8v zhf = *(const s8v*)&zh[idx];
            s8v zlf = *(const s8v*)&zl[idx];
            oacc[cf] = __builtin_amdgcn_mfma_f32_16x16x32_bf16(va, zhf, oacc[cf], 0, 0, 0);
            oacc[cf] = __builtin_amdgcn_mfma_f32_16x16x32_bf16(va, zlf, oacc[cf], 0, 0, 0);
            oacc[cf] = __builtin_amdgcn_mfma_f32_16x16x32_bf16(vb, zhf, oacc[cf], 0, 0, 0);
        }
    }
    __syncthreads();

    // ---- epilogue: scale by 1/l, pack hi/lo, store ----
#pragma unroll
    for (int cf = 0; cf < 4; ++cf) {
        const int tokL = cf * 16 + l15;
        float il = invl[tokL];
        float o0 = oacc[cf][0] * il, o1 = oacc[cf][1] * il;
        float o2 = oacc[cf][2] * il, o3 = oacc[cf][3] * il;
        u16 h0 = f2bf(o0), h1 = f2bf(o1), h2 = f2bf(o2), h3 = f2bf(o3);
        uint2 ph, pl;
        ph.x = (unsigned int)h0 | ((unsigned int)h1 << 16);
        ph.y = (unsigned int)h2 | ((unsigned int)h3 << 16);
        pl.x = (unsigned int)f2bf(o0 - bf2f(h0)) | ((unsigned int)f2bf(o1 - bf2f(h1)) << 16);
        pl.y = (unsigned int)f2bf(o2 - bf2f(h2)) | ((unsigned int)f2bf(o3 - bf2f(h3)) << 16);
        size_t po = ((size_t)(bb * NN + tok0 + tokL)) * 1024 + hh * 64 + w * 16 + 4 * g;
        *(uint2*)(Phi + po) = ph;
        *(uint2*)(Plo + po) = pl;
    }
}

// ---------------- launcher -------------------------------------------------
extern "C" void kernel_launch(void* const* d_in, const int* in_sizes, int n_in,
                              void* d_out, int out_size, void* d_ws, size_t ws_size,
                              hipStream_t stream) {
    const int* cluster  = (const int*)d_in[0];
    const float* x      = (const float*)d_in[1];
    const float* w_q    = (const float*)d_in[2];
    const float* w_kv   = (const float*)d_in[3];
    const float* w_proj = (const float*)d_in[4];
    const float* b_proj = (const float*)d_in[5];
    float* out = (float*)d_out;

    // layout (~312 MiB)
    const size_t SZ_H  = (size_t)MM * 1024 * 2;      // 64 MiB
    const size_t SZ_W  = (size_t)4096 * 1024 * 2;    // 8 MiB
    const size_t SZ_XS = (size_t)2048 * 1024 * 2;    // 4 MiB
    const size_t SZ_CS = (size_t)2048 * 2048 * 4;    // 16 MiB
    const size_t SZ_KV = (size_t)128 * NCL * 64 * 2; // 4 MiB

    char* p = (char*)d_ws;
    u16* Xhi = (u16*)p;   p += SZ_H;    // reused as Phi after attention
    u16* Xlo = (u16*)p;   p += SZ_H;    // reused as Plo
    u16* Qhi = (u16*)p;   p += SZ_H;
    u16* Qlo = (u16*)p;   p += SZ_H;
    u16* Wthi = (u16*)p;  p += SZ_W;
    u16* Wtlo = (u16*)p;  p += SZ_W;
    u16* XShi = (u16*)p;  p += SZ_XS;
    u16* XSlo = (u16*)p;  p += SZ_XS;
    float* Csum = (float*)p; p += SZ_CS;
    u16* Khi = (u16*)p;   p += SZ_KV;
    u16* Klo = (u16*)p;   p += SZ_KV;
    u16* Vthi = (u16*)p;  p += SZ_KV;
    u16* Vtlo = (u16*)p;  p += SZ_KV;
    float2* tab = (float2*)p; p += 2048 * sizeof(float2);
    int* counts = (int*)p;

    hipMemsetAsync(counts, 0, BB * NCL * sizeof(int), stream);
    count_k<<<MM / 256, 256, 0, stream>>>(cluster, counts);
    tab_k<<<8, 256, 0, stream>>>(counts, tab);

    convx_k<<<(size_t)MM * KK / 1024, 256, 0, stream>>>(x, Xhi, Xlo);
    convw_k<<<dim3(32, 32), 256, 0, stream>>>(w_q, 1024, Wthi, Wtlo);
    convw_k<<<dim3(64, 32), 256, 0, stream>>>(w_kv, 2048, Wthi + (size_t)1024 * KK, Wtlo + (size_t)1024 * KK);
    convw_k<<<dim3(32, 32), 256, 0, stream>>>(w_proj, 1024, Wthi + (size_t)3072 * KK, Wtlo + (size_t)3072 * KK);

    xsum_k<<<BB * NCL, 256, 0, stream>>>(x, cluster, XShi, XSlo);

    // Q = X @ Wq^T  -> bf16 hi/lo
    hgemm_k<2><<<dim3(8, 256), 256, 0, stream>>>(Xhi, Xlo, Wthi, Wtlo,
                                                 nullptr, 0, nullptr, Qhi, Qlo);
    // Csum = XS @ Wkv^T (ksum | vsum), fp32
    hgemm_k<0><<<dim3(16, 16), 256, 0, stream>>>(XShi, XSlo,
                                                 Wthi + (size_t)1024 * KK, Wtlo + (size_t)1024 * KK,
                                                 Csum, 2048, nullptr, nullptr, nullptr);
    // K / V^T in MFMA-friendly pre-swizzled layouts
    convk_k<<<128, 256, 0, stream>>>(Csum, Khi, Klo);
    convv_k<<<128, 256, 0, stream>>>(Csum, Vthi, Vtlo);

    // fused attention -> P (bf16 hi/lo, aliases X buffers)
    fattn_k<<<dim3(64, HEADS, BB), 256, 0, stream>>>(Qhi, Qlo, Khi, Klo,
                                                     Vthi, Vtlo, tab, Xhi, Xlo);
    // out = P @ Wproj^T + bias
    hgemm_k<1><<<dim3(8, 256), 256, 0, stream>>>(Xhi, Xlo,
                                                 Wthi + (size_t)3072 * KK, Wtlo + (size_t)3072 * KK,
                                                 out, 1024, b_proj, nullptr, nullptr);
}

// Round 7
// 995.980 us; speedup vs baseline: 5.0197x; 1.0169x over previous
//
#include <hip/hip_runtime.h>
#include <hip/hip_bf16.h>
#include <math.h>

#define HEADS 16
#define NCL 256
#define BB 8
#define NN 4096
#define DD 1024
#define DH 64
#define MM (BB*NN)   // 32768
#define KK 1024

typedef unsigned short u16;
typedef __attribute__((ext_vector_type(8))) short s8v;     // 8 bf16 (4 VGPRs)
typedef __attribute__((ext_vector_type(4))) float f32x4;   // MFMA C/D

__device__ __forceinline__ float bf2f(u16 u) {
    union { unsigned int i; float f; } v; v.i = ((unsigned int)u) << 16; return v.f;
}
__device__ __forceinline__ u16 f2bf(float x) {   // round-to-nearest-even
    union { float f; unsigned int i; } v; v.f = x;
    unsigned int u = v.i;
    return (u16)((u + 0x7FFFu + ((u >> 16) & 1u)) >> 16);
}
__device__ __forceinline__ void gl16(const u16* g, u16* l) {
    __builtin_amdgcn_global_load_lds(
        (__attribute__((address_space(1))) void*)g,
        (__attribute__((address_space(3))) void*)l, 16, 0, 0);
}

// ---------------- cluster counts (int atomics = deterministic) -------------
__global__ __launch_bounds__(256) void count_k(const int* __restrict__ cluster,
                                               int* __restrict__ counts) {
    int i = blockIdx.x * 256 + threadIdx.x;
    if (i < BB * NN) {
        int b = i / NN;
        atomicAdd(counts + b * NCL + cluster[i], 1);
    }
}

// ---------------- per-(b,c) table: (0.125/cnt, cnt) ------------------------
__global__ __launch_bounds__(256) void tab_k(const int* __restrict__ counts,
                                             float2* __restrict__ tab) {
    int i = blockIdx.x * 256 + threadIdx.x;   // b*256 + c
    int n = counts[i];
    float2 t;
    t.x = n > 0 ? 0.125f / (float)n : 0.f;
    t.y = (float)n;
    tab[i] = t;
}

// ---------------- stable counting sort of token indices by cluster ---------
// one block per batch; thread c owns bin c. Ascending token order within a
// bin (same summation order as the old scan -> deterministic).
__global__ __launch_bounds__(256) void sortidx_k(const int* __restrict__ cluster,
                                                 const int* __restrict__ counts,
                                                 int* __restrict__ tokidx,
                                                 int* __restrict__ starts) {
    __shared__ int cl[NN];    // 16 KB
    __shared__ int pf[NCL];
    const int bb = blockIdx.x;
    const int tid = threadIdx.x;

    for (int i = tid; i < NN; i += 256) cl[i] = cluster[bb * NN + i];
    int myc = counts[bb * NCL + tid];
    pf[tid] = myc;
    __syncthreads();
    // Hillis-Steele inclusive scan (read-barrier-write-barrier per step)
    for (int off = 1; off < NCL; off <<= 1) {
        int v = (tid >= off) ? pf[tid - off] : 0;
        __syncthreads();
        pf[tid] += v;
        __syncthreads();
    }
    int start = pf[tid] - myc;   // exclusive prefix
    starts[bb * NCL + tid] = start;

    int rank = 0;
    for (int t = 0; t < NN; ++t) {
        if (cl[t] == tid) { tokidx[bb * NN + start + rank] = t; ++rank; }
    }
}

// ---------------- x -> bf16 hi/lo split ------------------------------------
__global__ __launch_bounds__(256) void convx_k(const float* __restrict__ x,
                                               u16* __restrict__ hi,
                                               u16* __restrict__ lo) {
    size_t i = ((size_t)blockIdx.x * 256 + threadIdx.x) * 4;
    float4 v = *(const float4*)(x + i);
    ushort4 h, l;
    h.x = f2bf(v.x); l.x = f2bf(v.x - bf2f(h.x));
    h.y = f2bf(v.y); l.y = f2bf(v.y - bf2f(h.y));
    h.z = f2bf(v.z); l.z = f2bf(v.z - bf2f(h.z));
    h.w = f2bf(v.w); l.w = f2bf(v.w - bf2f(h.w));
    *(ushort4*)(hi + i) = h;
    *(ushort4*)(lo + i) = l;
}

// ---------------- weight: [K=1024][N] fp32 -> [N][K] bf16 hi/lo ------------
__global__ __launch_bounds__(256) void convw_k(const float* __restrict__ w, int N,
                                               u16* __restrict__ thi,
                                               u16* __restrict__ tlo) {
    __shared__ float t[32][33];
    const int bx = blockIdx.x, by = blockIdx.y;
    const int lx = threadIdx.x & 31, ly = threadIdx.x >> 5;   // ly 0..7
#pragma unroll
    for (int p = 0; p < 4; ++p)
        t[p * 8 + ly][lx] = w[(size_t)(by * 32 + p * 8 + ly) * N + bx * 32 + lx];
    __syncthreads();
#pragma unroll
    for (int p = 0; p < 4; ++p) {
        int n = bx * 32 + p * 8 + ly;
        int k = by * 32 + lx;
        float v = t[lx][p * 8 + ly];
        u16 h = f2bf(v);
        thi[(size_t)n * KK + k] = h;
        tlo[(size_t)n * KK + k] = f2bf(v - bf2f(h));
    }
}

// ---------------- segment-sum of x via sorted index list -------------------
// block (b,c): loops over exactly cnt token rows (unconditional, pipelined).
__global__ __launch_bounds__(256) void xsum2_k(const float* __restrict__ x,
                                               const int* __restrict__ tokidx,
                                               const int* __restrict__ starts,
                                               const int* __restrict__ counts,
                                               u16* __restrict__ shi,
                                               u16* __restrict__ slo) {
    const int bb = blockIdx.x >> 8;
    const int c = blockIdx.x & (NCL - 1);
    const int tid = threadIdx.x;
    const int start = starts[bb * NCL + c];
    const int cnt = counts[bb * NCL + c];
    const int* ti = tokidx + bb * NN + start;

    float a[4] = {0.f, 0.f, 0.f, 0.f};
    for (int i = 0; i < cnt; ++i) {
        int t = ti[i];
        const float* xr = x + ((size_t)bb * NN + t) * DD;
#pragma unroll
        for (int j = 0; j < 4; ++j) a[j] += xr[tid + 256 * j];
    }
    size_t o = ((size_t)bb * NCL + c) * DD;
#pragma unroll
    for (int j = 0; j < 4; ++j) {
        u16 h = f2bf(a[j]);
        shi[o + tid + 256 * j] = h;
        slo[o + tid + 256 * j] = f2bf(a[j] - bf2f(h));
    }
}

// ---------------- Csum k-part -> K [b][h][256 cl][64] bf16 hi/lo, swizzled -
// 16B-unit u within each 128B row stored at u ^ (cl&7).
__global__ __launch_bounds__(256) void convk_k(const float* __restrict__ Csum,
                                               u16* __restrict__ khi,
                                               u16* __restrict__ klo) {
    const int bh = blockIdx.x;            // b*16 + h
    const int bb = bh >> 4, hh = bh & 15;
    const int tid = threadIdx.x;
#pragma unroll
    for (int i = 0; i < 8; ++i) {
        int ulin = tid + 256 * i;          // cl*8 + u
        int c = ulin >> 3, u = ulin & 7;
        const float* src = Csum + ((size_t)(bb * NCL + c)) * 2048 + hh * 64 + u * 8;
        float4 v0 = *(const float4*)src;
        float4 v1 = *(const float4*)(src + 4);
        size_t o = ((size_t)bh * NCL + c) * 64 + ((u ^ (c & 7)) << 3);
        ushort4 h0, l0, h1, l1;
        h0.x = f2bf(v0.x); l0.x = f2bf(v0.x - bf2f(h0.x));
        h0.y = f2bf(v0.y); l0.y = f2bf(v0.y - bf2f(h0.y));
        h0.z = f2bf(v0.z); l0.z = f2bf(v0.z - bf2f(h0.z));
        h0.w = f2bf(v0.w); l0.w = f2bf(v0.w - bf2f(h0.w));
        h1.x = f2bf(v1.x); l1.x = f2bf(v1.x - bf2f(h1.x));
        h1.y = f2bf(v1.y); l1.y = f2bf(v1.y - bf2f(h1.y));
        h1.z = f2bf(v1.z); l1.z = f2bf(v1.z - bf2f(h1.z));
        h1.w = f2bf(v1.w); l1.w = f2bf(v1.w - bf2f(h1.w));
        *(ushort4*)(khi + o) = h0; *(ushort4*)(khi + o + 4) = h1;
        *(ushort4*)(klo + o) = l0; *(ushort4*)(klo + o + 4) = l1;
    }
}

// ---------------- Csum v-part -> V^T [b][h][64 d][256 cl] hi/lo, swizzled --
__global__ __launch_bounds__(256) void convv_k(const float* __restrict__ Csum,
                                               u16* __restrict__ vthi,
                                               u16* __restrict__ vtlo) {
    __shared__ float vb[NCL][65];   // 66.5 KB
    const int bh = blockIdx.x;
    const int bb = bh >> 4, hh = bh & 15;
    const int tid = threadIdx.x;
    const int d0 = tid & 63;
#pragma unroll
    for (int i = 0; i < 64; ++i) {
        int c = (tid >> 6) + i * 4;
        vb[c][d0] = Csum[((size_t)(bb * NCL + c)) * 2048 + 1024 + hh * 64 + d0];
    }
    __syncthreads();
    const int d = tid >> 2;
    const int uq = tid & 3;
#pragma unroll
    for (int j = 0; j < 8; ++j) {
        int u = uq * 8 + j;                // original unit (8 clusters)
        int c0 = u * 8;
        float v[8];
#pragma unroll
        for (int e = 0; e < 8; ++e) v[e] = vb[c0 + e][d];
        ushort4 h0, l0, h1, l1;
        h0.x = f2bf(v[0]); l0.x = f2bf(v[0] - bf2f(h0.x));
        h0.y = f2bf(v[1]); l0.y = f2bf(v[1] - bf2f(h0.y));
        h0.z = f2bf(v[2]); l0.z = f2bf(v[2] - bf2f(h0.z));
        h0.w = f2bf(v[3]); l0.w = f2bf(v[3] - bf2f(h0.w));
        h1.x = f2bf(v[4]); l1.x = f2bf(v[4] - bf2f(h1.x));
        h1.y = f2bf(v[5]); l1.y = f2bf(v[5] - bf2f(h1.y));
        h1.z = f2bf(v[6]); l1.z = f2bf(v[6] - bf2f(h1.z));
        h1.w = f2bf(v[7]); l1.w = f2bf(v[7] - bf2f(h1.w));
        int usw = (u & 24) | ((u ^ d) & 7);  // low3 bits XOR'd within 8-group
        size_t o = ((size_t)bh * 64 + d) * 256 + usw * 8;
        *(ushort4*)(vthi + o) = h0; *(ushort4*)(vthi + o + 4) = h1;
        *(ushort4*)(vtlo + o) = l0; *(ushort4*)(vtlo + o + 4) = l1;
    }
}

// ---------------- split-bf16 MFMA GEMM -------------------------------------
// SWZ=1: 1-D grid of 2048 blocks, XCD-aware bijective remap so the 8
// col-blocks sharing an A row-panel land on the SAME XCD (L2 reuse).
template<int OUT, int SWZ>
__global__ __launch_bounds__(256) void hgemm_k(
        const u16* __restrict__ Ahi, const u16* __restrict__ Alo,
        const u16* __restrict__ Bhi, const u16* __restrict__ Blo,
        float* __restrict__ C, int ldc, const float* __restrict__ bias,
        u16* __restrict__ Ohi, u16* __restrict__ Olo) {
    __shared__ u16 sh[4][128 * 32];

    const int tid = threadIdx.x;
    const int lane = tid & 63;
    const int wid = tid >> 6;
    const int wm = wid >> 1, wn = wid & 1;

    int bx, by;
    if constexpr (SWZ) {
        int lin = blockIdx.x;                       // nwg = 2048, 2048 % 8 == 0
        int swz = ((lin & 7) << 8) + (lin >> 3);    // XCD lin%8 owns chunk lin%8
        bx = swz & 7; by = swz >> 3;
    } else {
        bx = blockIdx.x; by = blockIdx.y;
    }
    const size_t row0 = (size_t)by * 128;
    const size_t col0 = (size_t)bx * 128;

    const int sr = tid >> 2;
    const int sq = tid & 3;
    const int qs = sq ^ ((sr >> 1) & 3);

    const u16* ga0 = Ahi + (row0 + sr) * KK + qs * 8;
    const u16* ga1 = ga0 + (size_t)64 * KK;
    const u16* gA0 = Alo + (row0 + sr) * KK + qs * 8;
    const u16* gA1 = gA0 + (size_t)64 * KK;
    const u16* gb0 = Bhi + (col0 + sr) * KK + qs * 8;
    const u16* gb1 = gb0 + (size_t)64 * KK;
    const u16* gB0 = Blo + (col0 + sr) * KK + qs * 8;
    const u16* gB1 = gB0 + (size_t)64 * KK;

    u16* d = (u16*)sh + tid * 8;

    const int rA = wm * 64 + (lane & 15);
    const int rB = wn * 64 + (lane & 15);
    const int aoff = rA * 32 + (((lane >> 4) ^ ((rA >> 1) & 3)) * 8);
    const int boff = rB * 32 + (((lane >> 4) ^ ((rB >> 1) & 3)) * 8);

    f32x4 acc[4][4] = {};

    for (int k0 = 0; k0 < KK; k0 += 32) {
        gl16(ga0 + k0, d);
        gl16(ga1 + k0, d + 2048);
        gl16(gA0 + k0, d + 4096);
        gl16(gA1 + k0, d + 6144);
        gl16(gb0 + k0, d + 8192);
        gl16(gb1 + k0, d + 10240);
        gl16(gB0 + k0, d + 12288);
        gl16(gB1 + k0, d + 14336);
        __syncthreads();
        s8v ah[4], al[4], bh[4], bl[4];
#pragma unroll
        for (int i = 0; i < 4; ++i) {
            ah[i] = *(const s8v*)&sh[0][aoff + i * 512];
            al[i] = *(const s8v*)&sh[1][aoff + i * 512];
            bh[i] = *(const s8v*)&sh[2][boff + i * 512];
            bl[i] = *(const s8v*)&sh[3][boff + i * 512];
        }
#pragma unroll
        for (int i = 0; i < 4; ++i)
#pragma unroll
            for (int j = 0; j < 4; ++j) {
                acc[i][j] = __builtin_amdgcn_mfma_f32_16x16x32_bf16(ah[i], bh[j], acc[i][j], 0, 0, 0);
                acc[i][j] = __builtin_amdgcn_mfma_f32_16x16x32_bf16(ah[i], bl[j], acc[i][j], 0, 0, 0);
                acc[i][j] = __builtin_amdgcn_mfma_f32_16x16x32_bf16(al[i], bh[j], acc[i][j], 0, 0, 0);
            }
        __syncthreads();
    }

    const int fr = (lane >> 4) * 4;
    const int fc = lane & 15;

    if constexpr (OUT == 2) {
#pragma unroll
        for (int i = 0; i < 4; ++i)
#pragma unroll
            for (int j = 0; j < 4; ++j) {
                size_t rbase = row0 + wm * 64 + i * 16 + fr;
                size_t cidx = col0 + wn * 64 + j * 16 + fc;
#pragma unroll
                for (int g = 0; g < 4; ++g) {
                    float o = acc[i][j][g];
                    u16 h = f2bf(o);
                    u16 l2 = f2bf(o - bf2f(h));
                    size_t idx = (rbase + g) * 1024 + cidx;
                    Ohi[idx] = h;
                    Olo[idx] = l2;
                }
            }
    } else {
        float bj[4] = {0.f, 0.f, 0.f, 0.f};
        if constexpr (OUT == 1) {
#pragma unroll
            for (int j = 0; j < 4; ++j) bj[j] = bias[col0 + wn * 64 + j * 16 + fc];
        }
#pragma unroll
        for (int i = 0; i < 4; ++i)
#pragma unroll
            for (int j = 0; j < 4; ++j) {
                size_t rbase = row0 + wm * 64 + i * 16 + fr;
                size_t cidx = col0 + wn * 64 + j * 16 + fc;
#pragma unroll
                for (int g = 0; g < 4; ++g)
                    C[(rbase + g) * (size_t)ldc + cidx] = acc[i][j][g] + bj[j];
            }
    }
}

// ---------------- fused MFMA attention (unchanged from round 6) ------------
__global__ __launch_bounds__(256) void fattn_k(const u16* __restrict__ Qhi,
                                               const u16* __restrict__ Qlo,
                                               const u16* __restrict__ Khi,
                                               const u16* __restrict__ Klo,
                                               const u16* __restrict__ Vthi,
                                               const u16* __restrict__ Vtlo,
                                               const float2* __restrict__ tab,
                                               u16* __restrict__ Phi,
                                               u16* __restrict__ Plo) {
    __shared__ u16 zh[64 * 256];     // 32 KB  [tokL][cl], 16B-unit ^ (tokL&7)
    __shared__ u16 zl[64 * 256];     // 32 KB
    __shared__ float lpart[4][64];
    __shared__ float invl[64];

    const int tid = threadIdx.x;
    const int lane = tid & 63;
    const int w = tid >> 6;
    const int g = lane >> 4;
    const int l15 = lane & 15;
    const int hh = blockIdx.y, bb = blockIdx.z;
    const int bh = bb * 16 + hh;
    const int tok0 = blockIdx.x * 64;

    // ---- Q^T B-frags ----
    s8v qf[2][4][2];   // [ks][cf][hi/lo]
#pragma unroll
    for (int cf = 0; cf < 4; ++cf)
#pragma unroll
        for (int ks = 0; ks < 2; ++ks) {
            size_t qo = ((size_t)(bb * NN + tok0 + cf * 16 + l15)) * 1024
                        + hh * 64 + ks * 32 + g * 8;
            qf[ks][cf][0] = *(const s8v*)(Qhi + qo);
            qf[ks][cf][1] = *(const s8v*)(Qlo + qo);
        }

    // ---- QK^T: acc[f][cf] = S^T[cl 16-slice][tok 16-slice] ----
    f32x4 acc[4][4] = {};
    const size_t kbase = (size_t)bh * NCL * 64;
#pragma unroll
    for (int f = 0; f < 4; ++f) {
        const int cl = w * 64 + f * 16 + l15;
        s8v kf[2][2];
#pragma unroll
        for (int ks = 0; ks < 2; ++ks) {
            size_t ko = kbase + (size_t)cl * 64 + (((ks * 4 + g) ^ (l15 & 7)) << 3);
            kf[ks][0] = *(const s8v*)(Khi + ko);
            kf[ks][1] = *(const s8v*)(Klo + ko);
        }
#pragma unroll
        for (int cf = 0; cf < 4; ++cf)
#pragma unroll
            for (int ks = 0; ks < 2; ++ks) {
                acc[f][cf] = __builtin_amdgcn_mfma_f32_16x16x32_bf16(kf[ks][0], qf[ks][cf][0], acc[f][cf], 0, 0, 0);
                acc[f][cf] = __builtin_amdgcn_mfma_f32_16x16x32_bf16(kf[ks][0], qf[ks][cf][1], acc[f][cf], 0, 0, 0);
                acc[f][cf] = __builtin_amdgcn_mfma_f32_16x16x32_bf16(kf[ks][1], qf[ks][cf][0], acc[f][cf], 0, 0, 0);
            }
    }

    // ---- softmax weights ----
    float lp[4] = {0.f, 0.f, 0.f, 0.f};
#pragma unroll
    for (int f = 0; f < 4; ++f) {
        float2 t4[4];
#pragma unroll
        for (int r = 0; r < 4; ++r)
            t4[r] = tab[bb * NCL + w * 64 + f * 16 + 4 * g + r];
#pragma unroll
        for (int cf = 0; cf < 4; ++cf) {
            float z[4];
#pragma unroll
            for (int r = 0; r < 4; ++r) {
                float e = __expf(acc[f][cf][r] * t4[r].x);
                lp[cf] += t4[r].y * e;
                z[r] = t4[r].y > 0.f ? e : 0.f;
            }
            const int tokL = cf * 16 + l15;
            int idx = (tokL * 256 + w * 64 + f * 16 + 4 * g) ^ (8 * (l15 & 7));
            uint2 ph, pl;
            u16 h0 = f2bf(z[0]), h1 = f2bf(z[1]), h2 = f2bf(z[2]), h3 = f2bf(z[3]);
            ph.x = (unsigned int)h0 | ((unsigned int)h1 << 16);
            ph.y = (unsigned int)h2 | ((unsigned int)h3 << 16);
            pl.x = (unsigned int)f2bf(z[0] - bf2f(h0)) | ((unsigned int)f2bf(z[1] - bf2f(h1)) << 16);
            pl.y = (unsigned int)f2bf(z[2] - bf2f(h2)) | ((unsigned int)f2bf(z[3] - bf2f(h3)) << 16);
            *(uint2*)&zh[idx] = ph;
            *(uint2*)&zl[idx] = pl;
        }
    }
#pragma unroll
    for (int cf = 0; cf < 4; ++cf) {
        lp[cf] += __shfl_xor(lp[cf], 16);
        lp[cf] += __shfl_xor(lp[cf], 32);
    }
    if (lane < 16) {
#pragma unroll
        for (int cf = 0; cf < 4; ++cf) lpart[w][cf * 16 + lane] = lp[cf];
    }
    __syncthreads();

    if (w == 0)
        invl[lane] = 1.f / (lpart[0][lane] + lpart[1][lane] + lpart[2][lane] + lpart[3][lane]);

    // ---- PV: out^T[d 16-slice][tok] ----
    f32x4 oacc[4] = {};
    const size_t vbase = (size_t)bh * 64 * 256;
    const int dg = w * 16 + l15;
#pragma unroll
    for (int ks = 0; ks < 8; ++ks) {
        size_t vo = vbase + (size_t)dg * 256
                    + (((ks * 4 + g) & 24) | (((ks * 4 + g) ^ dg) & 7)) * 8;
        s8v va = *(const s8v*)(Vthi + vo);
        s8v vb = *(const s8v*)(Vtlo + vo);
#pragma unroll
        for (int cf = 0; cf < 4; ++cf) {
            int idx = ((cf * 16 + l15) * 256 + ks * 32 + g * 8) ^ (8 * (l15 & 7));
            s8v zhf = *(const s8v*)&zh[idx];
            s8v zlf = *(const s8v*)&zl[idx];
            oacc[cf] = __builtin_amdgcn_mfma_f32_16x16x32_bf16(va, zhf, oacc[cf], 0, 0, 0);
            oacc[cf] = __builtin_amdgcn_mfma_f32_16x16x32_bf16(va, zlf, oacc[cf], 0, 0, 0);
            oacc[cf] = __builtin_amdgcn_mfma_f32_16x16x32_bf16(vb, zhf, oacc[cf], 0, 0, 0);
        }
    }
    __syncthreads();

    // ---- epilogue ----
#pragma unroll
    for (int cf = 0; cf < 4; ++cf) {
        const int tokL = cf * 16 + l15;
        float il = invl[tokL];
        float o0 = oacc[cf][0] * il, o1 = oacc[cf][1] * il;
        float o2 = oacc[cf][2] * il, o3 = oacc[cf][3] * il;
        u16 h0 = f2bf(o0), h1 = f2bf(o1), h2 = f2bf(o2), h3 = f2bf(o3);
        uint2 ph, pl;
        ph.x = (unsigned int)h0 | ((unsigned int)h1 << 16);
        ph.y = (unsigned int)h2 | ((unsigned int)h3 << 16);
        pl.x = (unsigned int)f2bf(o0 - bf2f(h0)) | ((unsigned int)f2bf(o1 - bf2f(h1)) << 16);
        pl.y = (unsigned int)f2bf(o2 - bf2f(h2)) | ((unsigned int)f2bf(o3 - bf2f(h3)) << 16);
        size_t po = ((size_t)(bb * NN + tok0 + tokL)) * 1024 + hh * 64 + w * 16 + 4 * g;
        *(uint2*)(Phi + po) = ph;
        *(uint2*)(Plo + po) = pl;
    }
}

// ---------------- launcher -------------------------------------------------
extern "C" void kernel_launch(void* const* d_in, const int* in_sizes, int n_in,
                              void* d_out, int out_size, void* d_ws, size_t ws_size,
                              hipStream_t stream) {
    const int* cluster  = (const int*)d_in[0];
    const float* x      = (const float*)d_in[1];
    const float* w_q    = (const float*)d_in[2];
    const float* w_kv   = (const float*)d_in[3];
    const float* w_proj = (const float*)d_in[4];
    const float* b_proj = (const float*)d_in[5];
    float* out = (float*)d_out;

    // layout (~312 MiB)
    const size_t SZ_H  = (size_t)MM * 1024 * 2;      // 64 MiB
    const size_t SZ_W  = (size_t)4096 * 1024 * 2;    // 8 MiB
    const size_t SZ_XS = (size_t)2048 * 1024 * 2;    // 4 MiB
    const size_t SZ_CS = (size_t)2048 * 2048 * 4;    // 16 MiB
    const size_t SZ_KV = (size_t)128 * NCL * 64 * 2; // 4 MiB

    char* p = (char*)d_ws;
    u16* Xhi = (u16*)p;   p += SZ_H;    // reused as Phi after attention
    u16* Xlo = (u16*)p;   p += SZ_H;    // reused as Plo
    u16* Qhi = (u16*)p;   p += SZ_H;
    u16* Qlo = (u16*)p;   p += SZ_H;
    u16* Wthi = (u16*)p;  p += SZ_W;
    u16* Wtlo = (u16*)p;  p += SZ_W;
    u16* XShi = (u16*)p;  p += SZ_XS;
    u16* XSlo = (u16*)p;  p += SZ_XS;
    float* Csum = (float*)p; p += SZ_CS;
    u16* Khi = (u16*)p;   p += SZ_KV;
    u16* Klo = (u16*)p;   p += SZ_KV;
    u16* Vthi = (u16*)p;  p += SZ_KV;
    u16* Vtlo = (u16*)p;  p += SZ_KV;
    float2* tab = (float2*)p; p += 2048 * sizeof(float2);
    int* counts = (int*)p;   p += 2048 * sizeof(int);
    int* tokidx = (int*)p;   p += (size_t)BB * NN * sizeof(int);
    int* starts = (int*)p;

    hipMemsetAsync(counts, 0, BB * NCL * sizeof(int), stream);
    count_k<<<MM / 256, 256, 0, stream>>>(cluster, counts);
    tab_k<<<8, 256, 0, stream>>>(counts, tab);
    sortidx_k<<<BB, 256, 0, stream>>>(cluster, counts, tokidx, starts);

    convx_k<<<(size_t)MM * KK / 1024, 256, 0, stream>>>(x, Xhi, Xlo);
    convw_k<<<dim3(32, 32), 256, 0, stream>>>(w_q, 1024, Wthi, Wtlo);
    convw_k<<<dim3(64, 32), 256, 0, stream>>>(w_kv, 2048, Wthi + (size_t)1024 * KK, Wtlo + (size_t)1024 * KK);
    convw_k<<<dim3(32, 32), 256, 0, stream>>>(w_proj, 1024, Wthi + (size_t)3072 * KK, Wtlo + (size_t)3072 * KK);

    xsum2_k<<<BB * NCL, 256, 0, stream>>>(x, tokidx, starts, counts, XShi, XSlo);

    // Q = X @ Wq^T  -> bf16 hi/lo  (XCD-swizzled)
    hgemm_k<2, 1><<<2048, 256, 0, stream>>>(Xhi, Xlo, Wthi, Wtlo,
                                            nullptr, 0, nullptr, Qhi, Qlo);
    // Csum = XS @ Wkv^T (ksum | vsum), fp32
    hgemm_k<0, 0><<<dim3(16, 16), 256, 0, stream>>>(XShi, XSlo,
                                                    Wthi + (size_t)1024 * KK, Wtlo + (size_t)1024 * KK,
                                                    Csum, 2048, nullptr, nullptr, nullptr);
    // K / V^T in MFMA-friendly pre-swizzled layouts
    convk_k<<<128, 256, 0, stream>>>(Csum, Khi, Klo);
    convv_k<<<128, 256, 0, stream>>>(Csum, Vthi, Vtlo);

    // fused attention -> P (bf16 hi/lo, aliases X buffers)
    fattn_k<<<dim3(64, HEADS, BB), 256, 0, stream>>>(Qhi, Qlo, Khi, Klo,
                                                     Vthi, Vtlo, tab, Xhi, Xlo);
    // out = P @ Wproj^T + bias  (XCD-swizzled)
    hgemm_k<1, 1><<<2048, 256, 0, stream>>>(Xhi, Xlo,
                                            Wthi + (size_t)3072 * KK, Wtlo + (size_t)3072 * KK,
                                            out, 1024, b_proj, nullptr, nullptr);
}

// Round 8
// 888.323 us; speedup vs baseline: 5.6280x; 1.1212x over previous
//
#include <hip/hip_runtime.h>
#include <hip/hip_bf16.h>
#include <math.h>

#define HEADS 16
#define NCL 256
#define BB 8
#define NN 4096
#define DD 1024
#define DH 64
#define MM (BB*NN)   // 32768
#define KK 1024

typedef unsigned short u16;
typedef __attribute__((ext_vector_type(8))) short s8v;     // 8 bf16 (4 VGPRs)
typedef __attribute__((ext_vector_type(4))) float f32x4;   // MFMA C/D

__device__ __forceinline__ float bf2f(u16 u) {
    union { unsigned int i; float f; } v; v.i = ((unsigned int)u) << 16; return v.f;
}
__device__ __forceinline__ u16 f2bf(float x) {   // round-to-nearest-even
    union { float f; unsigned int i; } v; v.f = x;
    unsigned int u = v.i;
    return (u16)((u + 0x7FFFu + ((u >> 16) & 1u)) >> 16);
}
__device__ __forceinline__ void gl16(const u16* g, u16* l) {
    __builtin_amdgcn_global_load_lds(
        (__attribute__((address_space(1))) void*)g,
        (__attribute__((address_space(3))) void*)l, 16, 0, 0);
}

// ---------------- cluster counts (int atomics = deterministic) -------------
__global__ __launch_bounds__(256) void count_k(const int* __restrict__ cluster,
                                               int* __restrict__ counts) {
    int i = blockIdx.x * 256 + threadIdx.x;
    if (i < BB * NN) {
        int b = i / NN;
        atomicAdd(counts + b * NCL + cluster[i], 1);
    }
}

// ---------------- per-(b,c) table: (0.125/cnt, cnt) ------------------------
__global__ __launch_bounds__(256) void tab_k(const int* __restrict__ counts,
                                             float2* __restrict__ tab) {
    int i = blockIdx.x * 256 + threadIdx.x;   // b*256 + c
    int n = counts[i];
    float2 t;
    t.x = n > 0 ? 0.125f / (float)n : 0.f;
    t.y = (float)n;
    tab[i] = t;
}

// ---------------- stable counting sort of token indices by cluster ---------
// one block per batch; thread c owns bin c. Ascending token order within a
// bin (same summation order as the original scan -> deterministic).
// R7 fix: the scan reads cl[] in 16-wide register batches so the 16 ds_reads
// issue back-to-back (one lgkmcnt wait per batch) instead of one serially-
// dependent ds_read per token (~120 cyc each x 4096 = ~205 us on 8 blocks).
__global__ __launch_bounds__(256) void sortidx_k(const int* __restrict__ cluster,
                                                 const int* __restrict__ counts,
                                                 int* __restrict__ tokidx,
                                                 int* __restrict__ starts) {
    __shared__ int cl[NN];    // 16 KB
    __shared__ int pf[NCL];
    const int bb = blockIdx.x;
    const int tid = threadIdx.x;

    for (int i = tid; i < NN; i += 256) cl[i] = cluster[bb * NN + i];
    int myc = counts[bb * NCL + tid];
    pf[tid] = myc;
    __syncthreads();
    // Hillis-Steele inclusive scan (read-barrier-write-barrier per step)
    for (int off = 1; off < NCL; off <<= 1) {
        int v = (tid >= off) ? pf[tid - off] : 0;
        __syncthreads();
        pf[tid] += v;
        __syncthreads();
    }
    int start = pf[tid] - myc;   // exclusive prefix
    starts[bb * NCL + tid] = start;

    int* dst = tokidx + bb * NN + start;
    int rank = 0;
    for (int t0 = 0; t0 < NN; t0 += 16) {
        int c16[16];
#pragma unroll
        for (int j = 0; j < 16; ++j) c16[j] = cl[t0 + j];   // batched reads
#pragma unroll
        for (int j = 0; j < 16; ++j) {
            if (c16[j] == tid) { dst[rank] = t0 + j; ++rank; }
        }
    }
}

// ---------------- x -> bf16 hi/lo split ------------------------------------
__global__ __launch_bounds__(256) void convx_k(const float* __restrict__ x,
                                               u16* __restrict__ hi,
                                               u16* __restrict__ lo) {
    size_t i = ((size_t)blockIdx.x * 256 + threadIdx.x) * 4;
    float4 v = *(const float4*)(x + i);
    ushort4 h, l;
    h.x = f2bf(v.x); l.x = f2bf(v.x - bf2f(h.x));
    h.y = f2bf(v.y); l.y = f2bf(v.y - bf2f(h.y));
    h.z = f2bf(v.z); l.z = f2bf(v.z - bf2f(h.z));
    h.w = f2bf(v.w); l.w = f2bf(v.w - bf2f(h.w));
    *(ushort4*)(hi + i) = h;
    *(ushort4*)(lo + i) = l;
}

// ---------------- weight: [K=1024][N] fp32 -> [N][K] bf16 hi/lo ------------
__global__ __launch_bounds__(256) void convw_k(const float* __restrict__ w, int N,
                                               u16* __restrict__ thi,
                                               u16* __restrict__ tlo) {
    __shared__ float t[32][33];
    const int bx = blockIdx.x, by = blockIdx.y;
    const int lx = threadIdx.x & 31, ly = threadIdx.x >> 5;   // ly 0..7
#pragma unroll
    for (int p = 0; p < 4; ++p)
        t[p * 8 + ly][lx] = w[(size_t)(by * 32 + p * 8 + ly) * N + bx * 32 + lx];
    __syncthreads();
#pragma unroll
    for (int p = 0; p < 4; ++p) {
        int n = bx * 32 + p * 8 + ly;
        int k = by * 32 + lx;
        float v = t[lx][p * 8 + ly];
        u16 h = f2bf(v);
        thi[(size_t)n * KK + k] = h;
        tlo[(size_t)n * KK + k] = f2bf(v - bf2f(h));
    }
}

// ---------------- segment-sum of x via sorted index list -------------------
// block (b,c): loops over exactly cnt token rows (unconditional, pipelined).
__global__ __launch_bounds__(256) void xsum2_k(const float* __restrict__ x,
                                               const int* __restrict__ tokidx,
                                               const int* __restrict__ starts,
                                               const int* __restrict__ counts,
                                               u16* __restrict__ shi,
                                               u16* __restrict__ slo) {
    const int bb = blockIdx.x >> 8;
    const int c = blockIdx.x & (NCL - 1);
    const int tid = threadIdx.x;
    const int start = starts[bb * NCL + c];
    const int cnt = counts[bb * NCL + c];
    const int* ti = tokidx + bb * NN + start;

    float a[4] = {0.f, 0.f, 0.f, 0.f};
    for (int i = 0; i < cnt; ++i) {
        int t = ti[i];
        const float* xr = x + ((size_t)bb * NN + t) * DD;
#pragma unroll
        for (int j = 0; j < 4; ++j) a[j] += xr[tid + 256 * j];
    }
    size_t o = ((size_t)bb * NCL + c) * DD;
#pragma unroll
    for (int j = 0; j < 4; ++j) {
        u16 h = f2bf(a[j]);
        shi[o + tid + 256 * j] = h;
        slo[o + tid + 256 * j] = f2bf(a[j] - bf2f(h));
    }
}

// ---------------- Csum k-part -> K [b][h][256 cl][64] bf16 hi/lo, swizzled -
// 16B-unit u within each 128B row stored at u ^ (cl&7).
__global__ __launch_bounds__(256) void convk_k(const float* __restrict__ Csum,
                                               u16* __restrict__ khi,
                                               u16* __restrict__ klo) {
    const int bh = blockIdx.x;            // b*16 + h
    const int bb = bh >> 4, hh = bh & 15;
    const int tid = threadIdx.x;
#pragma unroll
    for (int i = 0; i < 8; ++i) {
        int ulin = tid + 256 * i;          // cl*8 + u
        int c = ulin >> 3, u = ulin & 7;
        const float* src = Csum + ((size_t)(bb * NCL + c)) * 2048 + hh * 64 + u * 8;
        float4 v0 = *(const float4*)src;
        float4 v1 = *(const float4*)(src + 4);
        size_t o = ((size_t)bh * NCL + c) * 64 + ((u ^ (c & 7)) << 3);
        ushort4 h0, l0, h1, l1;
        h0.x = f2bf(v0.x); l0.x = f2bf(v0.x - bf2f(h0.x));
        h0.y = f2bf(v0.y); l0.y = f2bf(v0.y - bf2f(h0.y));
        h0.z = f2bf(v0.z); l0.z = f2bf(v0.z - bf2f(h0.z));
        h0.w = f2bf(v0.w); l0.w = f2bf(v0.w - bf2f(h0.w));
        h1.x = f2bf(v1.x); l1.x = f2bf(v1.x - bf2f(h1.x));
        h1.y = f2bf(v1.y); l1.y = f2bf(v1.y - bf2f(h1.y));
        h1.z = f2bf(v1.z); l1.z = f2bf(v1.z - bf2f(h1.z));
        h1.w = f2bf(v1.w); l1.w = f2bf(v1.w - bf2f(h1.w));
        *(ushort4*)(khi + o) = h0; *(ushort4*)(khi + o + 4) = h1;
        *(ushort4*)(klo + o) = l0; *(ushort4*)(klo + o + 4) = l1;
    }
}

// ---------------- Csum v-part -> V^T [b][h][64 d][256 cl] hi/lo, swizzled --
__global__ __launch_bounds__(256) void convv_k(const float* __restrict__ Csum,
                                               u16* __restrict__ vthi,
                                               u16* __restrict__ vtlo) {
    __shared__ float vb[NCL][65];   // 66.5 KB
    const int bh = blockIdx.x;
    const int bb = bh >> 4, hh = bh & 15;
    const int tid = threadIdx.x;
    const int d0 = tid & 63;
#pragma unroll
    for (int i = 0; i < 64; ++i) {
        int c = (tid >> 6) + i * 4;
        vb[c][d0] = Csum[((size_t)(bb * NCL + c)) * 2048 + 1024 + hh * 64 + d0];
    }
    __syncthreads();
    const int d = tid >> 2;
    const int uq = tid & 3;
#pragma unroll
    for (int j = 0; j < 8; ++j) {
        int u = uq * 8 + j;                // original unit (8 clusters)
        int c0 = u * 8;
        float v[8];
#pragma unroll
        for (int e = 0; e < 8; ++e) v[e] = vb[c0 + e][d];
        ushort4 h0, l0, h1, l1;
        h0.x = f2bf(v[0]); l0.x = f2bf(v[0] - bf2f(h0.x));
        h0.y = f2bf(v[1]); l0.y = f2bf(v[1] - bf2f(h0.y));
        h0.z = f2bf(v[2]); l0.z = f2bf(v[2] - bf2f(h0.z));
        h0.w = f2bf(v[3]); l0.w = f2bf(v[3] - bf2f(h0.w));
        h1.x = f2bf(v[4]); l1.x = f2bf(v[4] - bf2f(h1.x));
        h1.y = f2bf(v[5]); l1.y = f2bf(v[5] - bf2f(h1.y));
        h1.z = f2bf(v[6]); l1.z = f2bf(v[6] - bf2f(h1.z));
        h1.w = f2bf(v[7]); l1.w = f2bf(v[7] - bf2f(h1.w));
        int usw = (u & 24) | ((u ^ d) & 7);  // low3 bits XOR'd within 8-group
        size_t o = ((size_t)bh * 64 + d) * 256 + usw * 8;
        *(ushort4*)(vthi + o) = h0; *(ushort4*)(vthi + o + 4) = h1;
        *(ushort4*)(vtlo + o) = l0; *(ushort4*)(vtlo + o + 4) = l1;
    }
}

// ---------------- split-bf16 MFMA GEMM -------------------------------------
// SWZ=1: 1-D grid of 2048 blocks, XCD-aware bijective remap so the 8
// col-blocks sharing an A row-panel land on the SAME XCD (L2 reuse;
// FETCH_SIZE 533->132 MB verified R7).
template<int OUT, int SWZ>
__global__ __launch_bounds__(256) void hgemm_k(
        const u16* __restrict__ Ahi, const u16* __restrict__ Alo,
        const u16* __restrict__ Bhi, const u16* __restrict__ Blo,
        float* __restrict__ C, int ldc, const float* __restrict__ bias,
        u16* __restrict__ Ohi, u16* __restrict__ Olo) {
    __shared__ u16 sh[4][128 * 32];

    const int tid = threadIdx.x;
    const int lane = tid & 63;
    const int wid = tid >> 6;
    const int wm = wid >> 1, wn = wid & 1;

    int bx, by;
    if constexpr (SWZ) {
        int lin = blockIdx.x;                       // nwg = 2048, 2048 % 8 == 0
        int swz = ((lin & 7) << 8) + (lin >> 3);    // XCD lin%8 owns chunk lin%8
        bx = swz & 7; by = swz >> 3;
    } else {
        bx = blockIdx.x; by = blockIdx.y;
    }
    const size_t row0 = (size_t)by * 128;
    const size_t col0 = (size_t)bx * 128;

    const int sr = tid >> 2;
    const int sq = tid & 3;
    const int qs = sq ^ ((sr >> 1) & 3);

    const u16* ga0 = Ahi + (row0 + sr) * KK + qs * 8;
    const u16* ga1 = ga0 + (size_t)64 * KK;
    const u16* gA0 = Alo + (row0 + sr) * KK + qs * 8;
    const u16* gA1 = gA0 + (size_t)64 * KK;
    const u16* gb0 = Bhi + (col0 + sr) * KK + qs * 8;
    const u16* gb1 = gb0 + (size_t)64 * KK;
    const u16* gB0 = Blo + (col0 + sr) * KK + qs * 8;
    const u16* gB1 = gB0 + (size_t)64 * KK;

    u16* d = (u16*)sh + tid * 8;

    const int rA = wm * 64 + (lane & 15);
    const int rB = wn * 64 + (lane & 15);
    const int aoff = rA * 32 + (((lane >> 4) ^ ((rA >> 1) & 3)) * 8);
    const int boff = rB * 32 + (((lane >> 4) ^ ((rB >> 1) & 3)) * 8);

    f32x4 acc[4][4] = {};

    for (int k0 = 0; k0 < KK; k0 += 32) {
        gl16(ga0 + k0, d);
        gl16(ga1 + k0, d + 2048);
        gl16(gA0 + k0, d + 4096);
        gl16(gA1 + k0, d + 6144);
        gl16(gb0 + k0, d + 8192);
        gl16(gb1 + k0, d + 10240);
        gl16(gB0 + k0, d + 12288);
        gl16(gB1 + k0, d + 14336);
        __syncthreads();
        s8v ah[4], al[4], bh[4], bl[4];
#pragma unroll
        for (int i = 0; i < 4; ++i) {
            ah[i] = *(const s8v*)&sh[0][aoff + i * 512];
            al[i] = *(const s8v*)&sh[1][aoff + i * 512];
            bh[i] = *(const s8v*)&sh[2][boff + i * 512];
            bl[i] = *(const s8v*)&sh[3][boff + i * 512];
        }
#pragma unroll
        for (int i = 0; i < 4; ++i)
#pragma unroll
            for (int j = 0; j < 4; ++j) {
                acc[i][j] = __builtin_amdgcn_mfma_f32_16x16x32_bf16(ah[i], bh[j], acc[i][j], 0, 0, 0);
                acc[i][j] = __builtin_amdgcn_mfma_f32_16x16x32_bf16(ah[i], bl[j], acc[i][j], 0, 0, 0);
                acc[i][j] = __builtin_amdgcn_mfma_f32_16x16x32_bf16(al[i], bh[j], acc[i][j], 0, 0, 0);
            }
        __syncthreads();
    }

    const int fr = (lane >> 4) * 4;
    const int fc = lane & 15;

    if constexpr (OUT == 2) {
#pragma unroll
        for (int i = 0; i < 4; ++i)
#pragma unroll
            for (int j = 0; j < 4; ++j) {
                size_t rbase = row0 + wm * 64 + i * 16 + fr;
                size_t cidx = col0 + wn * 64 + j * 16 + fc;
#pragma unroll
                for (int g = 0; g < 4; ++g) {
                    float o = acc[i][j][g];
                    u16 h = f2bf(o);
                    u16 l2 = f2bf(o - bf2f(h));
                    size_t idx = (rbase + g) * 1024 + cidx;
                    Ohi[idx] = h;
                    Olo[idx] = l2;
                }
            }
    } else {
        float bj[4] = {0.f, 0.f, 0.f, 0.f};
        if constexpr (OUT == 1) {
#pragma unroll
            for (int j = 0; j < 4; ++j) bj[j] = bias[col0 + wn * 64 + j * 16 + fc];
        }
#pragma unroll
        for (int i = 0; i < 4; ++i)
#pragma unroll
            for (int j = 0; j < 4; ++j) {
                size_t rbase = row0 + wm * 64 + i * 16 + fr;
                size_t cidx = col0 + wn * 64 + j * 16 + fc;
#pragma unroll
                for (int g = 0; g < 4; ++g)
                    C[(rbase + g) * (size_t)ldc + cidx] = acc[i][j][g] + bj[j];
            }
    }
}

// ---------------- fused MFMA attention (unchanged) -------------------------
__global__ __launch_bounds__(256) void fattn_k(const u16* __restrict__ Qhi,
                                               const u16* __restrict__ Qlo,
                                               const u16* __restrict__ Khi,
                                               const u16* __restrict__ Klo,
                                               const u16* __restrict__ Vthi,
                                               const u16* __restrict__ Vtlo,
                                               const float2* __restrict__ tab,
                                               u16* __restrict__ Phi,
                                               u16* __restrict__ Plo) {
    __shared__ u16 zh[64 * 256];     // 32 KB  [tokL][cl], 16B-unit ^ (tokL&7)
    __shared__ u16 zl[64 * 256];     // 32 KB
    __shared__ float lpart[4][64];
    __shared__ float invl[64];

    const int tid = threadIdx.x;
    const int lane = tid & 63;
    const int w = tid >> 6;
    const int g = lane >> 4;
    const int l15 = lane & 15;
    const int hh = blockIdx.y, bb = blockIdx.z;
    const int bh = bb * 16 + hh;
    const int tok0 = blockIdx.x * 64;

    // ---- Q^T B-frags ----
    s8v qf[2][4][2];   // [ks][cf][hi/lo]
#pragma unroll
    for (int cf = 0; cf < 4; ++cf)
#pragma unroll
        for (int ks = 0; ks < 2; ++ks) {
            size_t qo = ((size_t)(bb * NN + tok0 + cf * 16 + l15)) * 1024
                        + hh * 64 + ks * 32 + g * 8;
            qf[ks][cf][0] = *(const s8v*)(Qhi + qo);
            qf[ks][cf][1] = *(const s8v*)(Qlo + qo);
        }

    // ---- QK^T: acc[f][cf] = S^T[cl 16-slice][tok 16-slice] ----
    f32x4 acc[4][4] = {};
    const size_t kbase = (size_t)bh * NCL * 64;
#pragma unroll
    for (int f = 0; f < 4; ++f) {
        const int cl = w * 64 + f * 16 + l15;
        s8v kf[2][2];
#pragma unroll
        for (int ks = 0; ks < 2; ++ks) {
            size_t ko = kbase + (size_t)cl * 64 + (((ks * 4 + g) ^ (l15 & 7)) << 3);
            kf[ks][0] = *(const s8v*)(Khi + ko);
            kf[ks][1] = *(const s8v*)(Klo + ko);
        }
#pragma unroll
        for (int cf = 0; cf < 4; ++cf)
#pragma unroll
            for (int ks = 0; ks < 2; ++ks) {
                acc[f][cf] = __builtin_amdgcn_mfma_f32_16x16x32_bf16(kf[ks][0], qf[ks][cf][0], acc[f][cf], 0, 0, 0);
                acc[f][cf] = __builtin_amdgcn_mfma_f32_16x16x32_bf16(kf[ks][0], qf[ks][cf][1], acc[f][cf], 0, 0, 0);
                acc[f][cf] = __builtin_amdgcn_mfma_f32_16x16x32_bf16(kf[ks][1], qf[ks][cf][0], acc[f][cf], 0, 0, 0);
            }
    }

    // ---- softmax weights ----
    float lp[4] = {0.f, 0.f, 0.f, 0.f};
#pragma unroll
    for (int f = 0; f < 4; ++f) {
        float2 t4[4];
#pragma unroll
        for (int r = 0; r < 4; ++r)
            t4[r] = tab[bb * NCL + w * 64 + f * 16 + 4 * g + r];
#pragma unroll
        for (int cf = 0; cf < 4; ++cf) {
            float z[4];
#pragma unroll
            for (int r = 0; r < 4; ++r) {
                float e = __expf(acc[f][cf][r] * t4[r].x);
                lp[cf] += t4[r].y * e;
                z[r] = t4[r].y > 0.f ? e : 0.f;
            }
            const int tokL = cf * 16 + l15;
            int idx = (tokL * 256 + w * 64 + f * 16 + 4 * g) ^ (8 * (l15 & 7));
            uint2 ph, pl;
            u16 h0 = f2bf(z[0]), h1 = f2bf(z[1]), h2 = f2bf(z[2]), h3 = f2bf(z[3]);
            ph.x = (unsigned int)h0 | ((unsigned int)h1 << 16);
            ph.y = (unsigned int)h2 | ((unsigned int)h3 << 16);
            pl.x = (unsigned int)f2bf(z[0] - bf2f(h0)) | ((unsigned int)f2bf(z[1] - bf2f(h1)) << 16);
            pl.y = (unsigned int)f2bf(z[2] - bf2f(h2)) | ((unsigned int)f2bf(z[3] - bf2f(h3)) << 16);
            *(uint2*)&zh[idx] = ph;
            *(uint2*)&zl[idx] = pl;
        }
    }
#pragma unroll
    for (int cf = 0; cf < 4; ++cf) {
        lp[cf] += __shfl_xor(lp[cf], 16);
        lp[cf] += __shfl_xor(lp[cf], 32);
    }
    if (lane < 16) {
#pragma unroll
        for (int cf = 0; cf < 4; ++cf) lpart[w][cf * 16 + lane] = lp[cf];
    }
    __syncthreads();

    if (w == 0)
        invl[lane] = 1.f / (lpart[0][lane] + lpart[1][lane] + lpart[2][lane] + lpart[3][lane]);

    // ---- PV: out^T[d 16-slice][tok] ----
    f32x4 oacc[4] = {};
    const size_t vbase = (size_t)bh * 64 * 256;
    const int dg = w * 16 + l15;
#pragma unroll
    for (int ks = 0; ks < 8; ++ks) {
        size_t vo = vbase + (size_t)dg * 256
                    + (((ks * 4 + g) & 24) | (((ks * 4 + g) ^ dg) & 7)) * 8;
        s8v va = *(const s8v*)(Vthi + vo);
        s8v vb = *(const s8v*)(Vtlo + vo);
#pragma unroll
        for (int cf = 0; cf < 4; ++cf) {
            int idx = ((cf * 16 + l15) * 256 + ks * 32 + g * 8) ^ (8 * (l15 & 7));
            s8v zhf = *(const s8v*)&zh[idx];
            s8v zlf = *(const s8v*)&zl[idx];
            oacc[cf] = __builtin_amdgcn_mfma_f32_16x16x32_bf16(va, zhf, oacc[cf], 0, 0, 0);
            oacc[cf] = __builtin_amdgcn_mfma_f32_16x16x32_bf16(va, zlf, oacc[cf], 0, 0, 0);
            oacc[cf] = __builtin_amdgcn_mfma_f32_16x16x32_bf16(vb, zhf, oacc[cf], 0, 0, 0);
        }
    }
    __syncthreads();

    // ---- epilogue ----
#pragma unroll
    for (int cf = 0; cf < 4; ++cf) {
        const int tokL = cf * 16 + l15;
        float il = invl[tokL];
        float o0 = oacc[cf][0] * il, o1 = oacc[cf][1] * il;
        float o2 = oacc[cf][2] * il, o3 = oacc[cf][3] * il;
        u16 h0 = f2bf(o0), h1 = f2bf(o1), h2 = f2bf(o2), h3 = f2bf(o3);
        uint2 ph, pl;
        ph.x = (unsigned int)h0 | ((unsigned int)h1 << 16);
        ph.y = (unsigned int)h2 | ((unsigned int)h3 << 16);
        pl.x = (unsigned int)f2bf(o0 - bf2f(h0)) | ((unsigned int)f2bf(o1 - bf2f(h1)) << 16);
        pl.y = (unsigned int)f2bf(o2 - bf2f(h2)) | ((unsigned int)f2bf(o3 - bf2f(h3)) << 16);
        size_t po = ((size_t)(bb * NN + tok0 + tokL)) * 1024 + hh * 64 + w * 16 + 4 * g;
        *(uint2*)(Phi + po) = ph;
        *(uint2*)(Plo + po) = pl;
    }
}

// ---------------- launcher -------------------------------------------------
extern "C" void kernel_launch(void* const* d_in, const int* in_sizes, int n_in,
                              void* d_out, int out_size, void* d_ws, size_t ws_size,
                              hipStream_t stream) {
    const int* cluster  = (const int*)d_in[0];
    const float* x      = (const float*)d_in[1];
    const float* w_q    = (const float*)d_in[2];
    const float* w_kv   = (const float*)d_in[3];
    const float* w_proj = (const float*)d_in[4];
    const float* b_proj = (const float*)d_in[5];
    float* out = (float*)d_out;

    // layout (~312 MiB)
    const size_t SZ_H  = (size_t)MM * 1024 * 2;      // 64 MiB
    const size_t SZ_W  = (size_t)4096 * 1024 * 2;    // 8 MiB
    const size_t SZ_XS = (size_t)2048 * 1024 * 2;    // 4 MiB
    const size_t SZ_CS = (size_t)2048 * 2048 * 4;    // 16 MiB
    const size_t SZ_KV = (size_t)128 * NCL * 64 * 2; // 4 MiB

    char* p = (char*)d_ws;
    u16* Xhi = (u16*)p;   p += SZ_H;    // reused as Phi after attention
    u16* Xlo = (u16*)p;   p += SZ_H;    // reused as Plo
    u16* Qhi = (u16*)p;   p += SZ_H;
    u16* Qlo = (u16*)p;   p += SZ_H;
    u16* Wthi = (u16*)p;  p += SZ_W;
    u16* Wtlo = (u16*)p;  p += SZ_W;
    u16* XShi = (u16*)p;  p += SZ_XS;
    u16* XSlo = (u16*)p;  p += SZ_XS;
    float* Csum = (float*)p; p += SZ_CS;
    u16* Khi = (u16*)p;   p += SZ_KV;
    u16* Klo = (u16*)p;   p += SZ_KV;
    u16* Vthi = (u16*)p;  p += SZ_KV;
    u16* Vtlo = (u16*)p;  p += SZ_KV;
    float2* tab = (float2*)p; p += 2048 * sizeof(float2);
    int* counts = (int*)p;   p += 2048 * sizeof(int);
    int* tokidx = (int*)p;   p += (size_t)BB * NN * sizeof(int);
    int* starts = (int*)p;

    hipMemsetAsync(counts, 0, BB * NCL * sizeof(int), stream);
    count_k<<<MM / 256, 256, 0, stream>>>(cluster, counts);
    tab_k<<<8, 256, 0, stream>>>(counts, tab);
    sortidx_k<<<BB, 256, 0, stream>>>(cluster, counts, tokidx, starts);

    convx_k<<<(size_t)MM * KK / 1024, 256, 0, stream>>>(x, Xhi, Xlo);
    convw_k<<<dim3(32, 32), 256, 0, stream>>>(w_q, 1024, Wthi, Wtlo);
    convw_k<<<dim3(64, 32), 256, 0, stream>>>(w_kv, 2048, Wthi + (size_t)1024 * KK, Wtlo + (size_t)1024 * KK);
    convw_k<<<dim3(32, 32), 256, 0, stream>>>(w_proj, 1024, Wthi + (size_t)3072 * KK, Wtlo + (size_t)3072 * KK);

    xsum2_k<<<BB * NCL, 256, 0, stream>>>(x, tokidx, starts, counts, XShi, XSlo);

    // Q = X @ Wq^T  -> bf16 hi/lo  (XCD-swizzled)
    hgemm_k<2, 1><<<2048, 256, 0, stream>>>(Xhi, Xlo, Wthi, Wtlo,
                                            nullptr, 0, nullptr, Qhi, Qlo);
    // Csum = XS @ Wkv^T (ksum | vsum), fp32
    hgemm_k<0, 0><<<dim3(16, 16), 256, 0, stream>>>(XShi, XSlo,
                                                    Wthi + (size_t)1024 * KK, Wtlo + (size_t)1024 * KK,
                                                    Csum, 2048, nullptr, nullptr, nullptr);
    // K / V^T in MFMA-friendly pre-swizzled layouts
    convk_k<<<128, 256, 0, stream>>>(Csum, Khi, Klo);
    convv_k<<<128, 256, 0, stream>>>(Csum, Vthi, Vtlo);

    // fused attention -> P (bf16 hi/lo, aliases X buffers)
    fattn_k<<<dim3(64, HEADS, BB), 256, 0, stream>>>(Qhi, Qlo, Khi, Klo,
                                                     Vthi, Vtlo, tab, Xhi, Xlo);
    // out = P @ Wproj^T + bias  (XCD-swizzled)
    hgemm_k<1, 1><<<2048, 256, 0, stream>>>(Xhi, Xlo,
                                            Wthi + (size_t)3072 * KK, Wtlo + (size_t)3072 * KK,
                                            out, 1024, b_proj, nullptr, nullptr);
}

// Round 9
// 795.818 us; speedup vs baseline: 6.2822x; 1.1162x over previous
//
#include <hip/hip_runtime.h>
#include <hip/hip_bf16.h>
#include <math.h>

#define HEADS 16
#define NCL 256
#define BB 8
#define NN 4096
#define DD 1024
#define DH 64
#define MM (BB*NN)   // 32768
#define KK 1024

typedef unsigned short u16;
typedef __attribute__((ext_vector_type(8))) short s8v;     // 8 bf16 (4 VGPRs)
typedef __attribute__((ext_vector_type(4))) float f32x4;   // MFMA C/D

__device__ __forceinline__ float bf2f(u16 u) {
    union { unsigned int i; float f; } v; v.i = ((unsigned int)u) << 16; return v.f;
}
__device__ __forceinline__ u16 f2bf(float x) {   // round-to-nearest-even
    union { float f; unsigned int i; } v; v.f = x;
    unsigned int u = v.i;
    return (u16)((u + 0x7FFFu + ((u >> 16) & 1u)) >> 16);
}
__device__ __forceinline__ void gl16(const u16* g, u16* l) {
    __builtin_amdgcn_global_load_lds(
        (__attribute__((address_space(1))) void*)g,
        (__attribute__((address_space(3))) void*)l, 16, 0, 0);
}

// ---------------- cluster counts (int atomics = deterministic) -------------
__global__ __launch_bounds__(256) void count_k(const int* __restrict__ cluster,
                                               int* __restrict__ counts) {
    int i = blockIdx.x * 256 + threadIdx.x;
    if (i < BB * NN) {
        int b = i / NN;
        atomicAdd(counts + b * NCL + cluster[i], 1);
    }
}

// ---------------- per-(b,c) table: (0.125/cnt, cnt) ------------------------
__global__ __launch_bounds__(256) void tab_k(const int* __restrict__ counts,
                                             float2* __restrict__ tab) {
    int i = blockIdx.x * 256 + threadIdx.x;   // b*256 + c
    int n = counts[i];
    float2 t;
    t.x = n > 0 ? 0.125f / (float)n : 0.f;
    t.y = (float)n;
    tab[i] = t;
}

// ---------------- stable counting sort of token indices by cluster ---------
__global__ __launch_bounds__(256) void sortidx_k(const int* __restrict__ cluster,
                                                 const int* __restrict__ counts,
                                                 int* __restrict__ tokidx,
                                                 int* __restrict__ starts) {
    __shared__ int cl[NN];    // 16 KB
    __shared__ int pf[NCL];
    const int bb = blockIdx.x;
    const int tid = threadIdx.x;

    for (int i = tid; i < NN; i += 256) cl[i] = cluster[bb * NN + i];
    int myc = counts[bb * NCL + tid];
    pf[tid] = myc;
    __syncthreads();
    for (int off = 1; off < NCL; off <<= 1) {
        int v = (tid >= off) ? pf[tid - off] : 0;
        __syncthreads();
        pf[tid] += v;
        __syncthreads();
    }
    int start = pf[tid] - myc;   // exclusive prefix
    starts[bb * NCL + tid] = start;

    int* dst = tokidx + bb * NN + start;
    int rank = 0;
    for (int t0 = 0; t0 < NN; t0 += 16) {
        int c16[16];
#pragma unroll
        for (int j = 0; j < 16; ++j) c16[j] = cl[t0 + j];   // batched reads
#pragma unroll
        for (int j = 0; j < 16; ++j) {
            if (c16[j] == tid) { dst[rank] = t0 + j; ++rank; }
        }
    }
}

// ---------------- x -> bf16 hi/lo split ------------------------------------
__global__ __launch_bounds__(256) void convx_k(const float* __restrict__ x,
                                               u16* __restrict__ hi,
                                               u16* __restrict__ lo) {
    size_t i = ((size_t)blockIdx.x * 256 + threadIdx.x) * 4;
    float4 v = *(const float4*)(x + i);
    ushort4 h, l;
    h.x = f2bf(v.x); l.x = f2bf(v.x - bf2f(h.x));
    h.y = f2bf(v.y); l.y = f2bf(v.y - bf2f(h.y));
    h.z = f2bf(v.z); l.z = f2bf(v.z - bf2f(h.z));
    h.w = f2bf(v.w); l.w = f2bf(v.w - bf2f(h.w));
    *(ushort4*)(hi + i) = h;
    *(ushort4*)(lo + i) = l;
}

// ---------------- weight: [K=1024][N] fp32 -> [N][K] bf16 hi/lo ------------
__global__ __launch_bounds__(256) void convw_k(const float* __restrict__ w, int N,
                                               u16* __restrict__ thi,
                                               u16* __restrict__ tlo) {
    __shared__ float t[32][33];
    const int bx = blockIdx.x, by = blockIdx.y;
    const int lx = threadIdx.x & 31, ly = threadIdx.x >> 5;   // ly 0..7
#pragma unroll
    for (int p = 0; p < 4; ++p)
        t[p * 8 + ly][lx] = w[(size_t)(by * 32 + p * 8 + ly) * N + bx * 32 + lx];
    __syncthreads();
#pragma unroll
    for (int p = 0; p < 4; ++p) {
        int n = bx * 32 + p * 8 + ly;
        int k = by * 32 + lx;
        float v = t[lx][p * 8 + ly];
        u16 h = f2bf(v);
        thi[(size_t)n * KK + k] = h;
        tlo[(size_t)n * KK + k] = f2bf(v - bf2f(h));
    }
}

// ---------------- segment-sum of x via sorted index list -------------------
__global__ __launch_bounds__(256) void xsum2_k(const float* __restrict__ x,
                                               const int* __restrict__ tokidx,
                                               const int* __restrict__ starts,
                                               const int* __restrict__ counts,
                                               u16* __restrict__ shi,
                                               u16* __restrict__ slo) {
    const int bb = blockIdx.x >> 8;
    const int c = blockIdx.x & (NCL - 1);
    const int tid = threadIdx.x;
    const int start = starts[bb * NCL + c];
    const int cnt = counts[bb * NCL + c];
    const int* ti = tokidx + bb * NN + start;

    float a[4] = {0.f, 0.f, 0.f, 0.f};
    for (int i = 0; i < cnt; ++i) {
        int t = ti[i];
        const float* xr = x + ((size_t)bb * NN + t) * DD;
#pragma unroll
        for (int j = 0; j < 4; ++j) a[j] += xr[tid + 256 * j];
    }
    size_t o = ((size_t)bb * NCL + c) * DD;
#pragma unroll
    for (int j = 0; j < 4; ++j) {
        u16 h = f2bf(a[j]);
        shi[o + tid + 256 * j] = h;
        slo[o + tid + 256 * j] = f2bf(a[j] - bf2f(h));
    }
}

// ---------------- Csum k-part -> K [b][h][256 cl][64] bf16 hi/lo, swizzled -
__global__ __launch_bounds__(256) void convk_k(const float* __restrict__ Csum,
                                               u16* __restrict__ khi,
                                               u16* __restrict__ klo) {
    const int bh = blockIdx.x;            // b*16 + h
    const int bb = bh >> 4, hh = bh & 15;
    const int tid = threadIdx.x;
#pragma unroll
    for (int i = 0; i < 8; ++i) {
        int ulin = tid + 256 * i;          // cl*8 + u
        int c = ulin >> 3, u = ulin & 7;
        const float* src = Csum + ((size_t)(bb * NCL + c)) * 2048 + hh * 64 + u * 8;
        float4 v0 = *(const float4*)src;
        float4 v1 = *(const float4*)(src + 4);
        size_t o = ((size_t)bh * NCL + c) * 64 + ((u ^ (c & 7)) << 3);
        ushort4 h0, l0, h1, l1;
        h0.x = f2bf(v0.x); l0.x = f2bf(v0.x - bf2f(h0.x));
        h0.y = f2bf(v0.y); l0.y = f2bf(v0.y - bf2f(h0.y));
        h0.z = f2bf(v0.z); l0.z = f2bf(v0.z - bf2f(h0.z));
        h0.w = f2bf(v0.w); l0.w = f2bf(v0.w - bf2f(h0.w));
        h1.x = f2bf(v1.x); l1.x = f2bf(v1.x - bf2f(h1.x));
        h1.y = f2bf(v1.y); l1.y = f2bf(v1.y - bf2f(h1.y));
        h1.z = f2bf(v1.z); l1.z = f2bf(v1.z - bf2f(h1.z));
        h1.w = f2bf(v1.w); l1.w = f2bf(v1.w - bf2f(h1.w));
        *(ushort4*)(khi + o) = h0; *(ushort4*)(khi + o + 4) = h1;
        *(ushort4*)(klo + o) = l0; *(ushort4*)(klo + o + 4) = l1;
    }
}

// ---------------- Csum v-part -> V^T [b][h][64 d][256 cl] hi/lo, swizzled --
__global__ __launch_bounds__(256) void convv_k(const float* __restrict__ Csum,
                                               u16* __restrict__ vthi,
                                               u16* __restrict__ vtlo) {
    __shared__ float vb[NCL][65];   // 66.5 KB
    const int bh = blockIdx.x;
    const int bb = bh >> 4, hh = bh & 15;
    const int tid = threadIdx.x;
    const int d0 = tid & 63;
#pragma unroll
    for (int i = 0; i < 64; ++i) {
        int c = (tid >> 6) + i * 4;
        vb[c][d0] = Csum[((size_t)(bb * NCL + c)) * 2048 + 1024 + hh * 64 + d0];
    }
    __syncthreads();
    const int d = tid >> 2;
    const int uq = tid & 3;
#pragma unroll
    for (int j = 0; j < 8; ++j) {
        int u = uq * 8 + j;                // original unit (8 clusters)
        int c0 = u * 8;
        float v[8];
#pragma unroll
        for (int e = 0; e < 8; ++e) v[e] = vb[c0 + e][d];
        ushort4 h0, l0, h1, l1;
        h0.x = f2bf(v[0]); l0.x = f2bf(v[0] - bf2f(h0.x));
        h0.y = f2bf(v[1]); l0.y = f2bf(v[1] - bf2f(h0.y));
        h0.z = f2bf(v[2]); l0.z = f2bf(v[2] - bf2f(h0.z));
        h0.w = f2bf(v[3]); l0.w = f2bf(v[3] - bf2f(h0.w));
        h1.x = f2bf(v[4]); l1.x = f2bf(v[4] - bf2f(h1.x));
        h1.y = f2bf(v[5]); l1.y = f2bf(v[5] - bf2f(h1.y));
        h1.z = f2bf(v[6]); l1.z = f2bf(v[6] - bf2f(h1.z));
        h1.w = f2bf(v[7]); l1.w = f2bf(v[7] - bf2f(h1.w));
        int usw = (u & 24) | ((u ^ d) & 7);  // low3 bits XOR'd within 8-group
        size_t o = ((size_t)bh * 64 + d) * 256 + usw * 8;
        *(ushort4*)(vthi + o) = h0; *(ushort4*)(vthi + o + 4) = h1;
        *(ushort4*)(vtlo + o) = l0; *(ushort4*)(vtlo + o + 4) = l1;
    }
}

// ---------------- 128-tile split-bf16 GEMM (kept for the small Csum GEMM) --
template<int OUT>
__global__ __launch_bounds__(256) void hgemm_k(
        const u16* __restrict__ Ahi, const u16* __restrict__ Alo,
        const u16* __restrict__ Bhi, const u16* __restrict__ Blo,
        float* __restrict__ C, int ldc, const float* __restrict__ bias,
        u16* __restrict__ Ohi, u16* __restrict__ Olo) {
    __shared__ u16 sh[4][128 * 32];

    const int tid = threadIdx.x;
    const int lane = tid & 63;
    const int wid = tid >> 6;
    const int wm = wid >> 1, wn = wid & 1;
    const size_t row0 = (size_t)blockIdx.y * 128;
    const size_t col0 = (size_t)blockIdx.x * 128;

    const int sr = tid >> 2;
    const int sq = tid & 3;
    const int qs = sq ^ ((sr >> 1) & 3);

    const u16* ga0 = Ahi + (row0 + sr) * KK + qs * 8;
    const u16* ga1 = ga0 + (size_t)64 * KK;
    const u16* gA0 = Alo + (row0 + sr) * KK + qs * 8;
    const u16* gA1 = gA0 + (size_t)64 * KK;
    const u16* gb0 = Bhi + (col0 + sr) * KK + qs * 8;
    const u16* gb1 = gb0 + (size_t)64 * KK;
    const u16* gB0 = Blo + (col0 + sr) * KK + qs * 8;
    const u16* gB1 = gB0 + (size_t)64 * KK;

    u16* d = (u16*)sh + tid * 8;

    const int rA = wm * 64 + (lane & 15);
    const int rB = wn * 64 + (lane & 15);
    const int aoff = rA * 32 + (((lane >> 4) ^ ((rA >> 1) & 3)) * 8);
    const int boff = rB * 32 + (((lane >> 4) ^ ((rB >> 1) & 3)) * 8);

    f32x4 acc[4][4] = {};

    for (int k0 = 0; k0 < KK; k0 += 32) {
        gl16(ga0 + k0, d);
        gl16(ga1 + k0, d + 2048);
        gl16(gA0 + k0, d + 4096);
        gl16(gA1 + k0, d + 6144);
        gl16(gb0 + k0, d + 8192);
        gl16(gb1 + k0, d + 10240);
        gl16(gB0 + k0, d + 12288);
        gl16(gB1 + k0, d + 14336);
        __syncthreads();
        s8v ah[4], al[4], bh[4], bl[4];
#pragma unroll
        for (int i = 0; i < 4; ++i) {
            ah[i] = *(const s8v*)&sh[0][aoff + i * 512];
            al[i] = *(const s8v*)&sh[1][aoff + i * 512];
            bh[i] = *(const s8v*)&sh[2][boff + i * 512];
            bl[i] = *(const s8v*)&sh[3][boff + i * 512];
        }
#pragma unroll
        for (int i = 0; i < 4; ++i)
#pragma unroll
            for (int j = 0; j < 4; ++j) {
                acc[i][j] = __builtin_amdgcn_mfma_f32_16x16x32_bf16(ah[i], bh[j], acc[i][j], 0, 0, 0);
                acc[i][j] = __builtin_amdgcn_mfma_f32_16x16x32_bf16(ah[i], bl[j], acc[i][j], 0, 0, 0);
                acc[i][j] = __builtin_amdgcn_mfma_f32_16x16x32_bf16(al[i], bh[j], acc[i][j], 0, 0, 0);
            }
        __syncthreads();
    }

    const int fr = (lane >> 4) * 4;
    const int fc = lane & 15;

    float bj[4] = {0.f, 0.f, 0.f, 0.f};
    if constexpr (OUT == 1) {
#pragma unroll
        for (int j = 0; j < 4; ++j) bj[j] = bias[col0 + wn * 64 + j * 16 + fc];
    }
#pragma unroll
    for (int i = 0; i < 4; ++i)
#pragma unroll
        for (int j = 0; j < 4; ++j) {
            size_t rbase = row0 + wm * 64 + i * 16 + fr;
            size_t cidx = col0 + wn * 64 + j * 16 + fc;
#pragma unroll
            for (int g = 0; g < 4; ++g)
                C[(rbase + g) * (size_t)ldc + cidx] = acc[i][j][g] + bj[j];
        }
}

// ---------------- 256-tile 8-wave phased split-bf16 GEMM (R9) --------------
// 256x256 tile, BK=32, 512 thr / 8 waves (2M x 4N), per-wave 128x64 out,
// 96 MFMA/wave/K-tile. Double-buffered LDS (2 x 64KB). Per K-tile: 4 phases
// {ds_read subtile, setprio(1), 24 MFMA, setprio(0), s_barrier}; staging for
// tile t+1 issued at phases 0-1 (4+4 gl16) -> the tile-end __syncthreads
// vmcnt-drain waits on ~3-phase-old loads (cheap). N is fixed at 1024
// (nbx=4). XCD-bijective block swizzle (nwg % 8 == 0).
// OUT: 1 = f32 + bias, 2 = bf16 hi/lo split (ld 1024)
template<int OUT>
__global__ __launch_bounds__(512) void hgemm256_k(
        const u16* __restrict__ Ahi, const u16* __restrict__ Alo,
        const u16* __restrict__ Bhi, const u16* __restrict__ Blo,
        float* __restrict__ C, int ldc, const float* __restrict__ bias,
        u16* __restrict__ Ohi, u16* __restrict__ Olo) {
    __shared__ u16 sh[2][4][8192];   // [buf][Ahi|Alo|Bhi|Blo][256*32]

    const int tid = threadIdx.x;
    const int lane = tid & 63;
    const int wid = tid >> 6;
    const int wm = wid >> 2, wn = wid & 3;
    const int l15 = lane & 15;

    // XCD swizzle: each XCD owns a contiguous chunk of swz (row-bands x 4 cols)
    const int nwg = gridDim.x;
    const int cpx = nwg >> 3;
    const int lin = blockIdx.x;
    const int swz = (lin & 7) * cpx + (lin >> 3);
    const int bx = swz & 3;          // N = 1024 -> 4 col tiles
    const int by = swz >> 2;

    const size_t row0 = (size_t)by * 256;
    const size_t col0 = (size_t)bx * 256;

    // staging map: thread -> row sr0 (+128 for second half), 16B quarter;
    // source k-quarter pre-swizzled by row (involution matches read side).
    const int sr0 = tid >> 2;            // 0..127
    const int qs0 = (tid & 3) ^ ((sr0 >> 1) & 3);
    const u16* pAh0 = Ahi + (row0 + sr0) * KK + qs0 * 8;
    const u16* pAh1 = pAh0 + (size_t)128 * KK;
    const u16* pAl0 = Alo + (row0 + sr0) * KK + qs0 * 8;
    const u16* pAl1 = pAl0 + (size_t)128 * KK;
    const u16* pBh0 = Bhi + (col0 + sr0) * KK + qs0 * 8;
    const u16* pBh1 = pBh0 + (size_t)128 * KK;
    const u16* pBl0 = Blo + (col0 + sr0) * KK + qs0 * 8;
    const u16* pBl1 = pBl0 + (size_t)128 * KK;

#define STG_A(bw, k) { u16* db = (u16*)sh + (bw) * 32768 + tid * 8;            \
        gl16(pAh0 + (k), db);            gl16(pAh1 + (k), db + 4096);          \
        gl16(pAl0 + (k), db + 8192);     gl16(pAl1 + (k), db + 12288); }
#define STG_B(bw, k) { u16* db = (u16*)sh + (bw) * 32768 + 16384 + tid * 8;    \
        gl16(pBh0 + (k), db);            gl16(pBh1 + (k), db + 4096);          \
        gl16(pBl0 + (k), db + 8192);     gl16(pBl1 + (k), db + 12288); }

    // read offsets (swizzle bits invariant under +16*frag)
    const int rA = wm * 128 + l15;
    const int rB = wn * 64 + l15;
    const int aoff = rA * 32 + (((lane >> 4) ^ ((rA >> 1) & 3)) * 8);
    const int boff = rB * 32 + (((lane >> 4) ^ ((rB >> 1) & 3)) * 8);

    f32x4 acc[8][4] = {};

    STG_A(0, 0);
    STG_B(0, 0);
    __syncthreads();

    int cur = 0;
    for (int kt = 0; kt < 32; ++kt) {
        const int kn = (kt + 1) * 32;
        const u16* br = (const u16*)sh + cur * 32768;
        const int bw = cur ^ 1;
        const bool st = kt < 31;

        // ---- phase 0: stage A(t+1), read B frags (regs, whole tile) + A 0/1
        if (st) STG_A(bw, kn);
        s8v bhf[4], blf[4];
#pragma unroll
        for (int ni = 0; ni < 4; ++ni) {
            bhf[ni] = *(const s8v*)(br + 16384 + boff + ni * 512);
            blf[ni] = *(const s8v*)(br + 24576 + boff + ni * 512);
        }
        {
            s8v ah0 = *(const s8v*)(br + aoff);
            s8v al0 = *(const s8v*)(br + 8192 + aoff);
            s8v ah1 = *(const s8v*)(br + aoff + 512);
            s8v al1 = *(const s8v*)(br + 8192 + aoff + 512);
            __builtin_amdgcn_s_setprio(1);
#pragma unroll
            for (int ni = 0; ni < 4; ++ni) {
                acc[0][ni] = __builtin_amdgcn_mfma_f32_16x16x32_bf16(ah0, bhf[ni], acc[0][ni], 0, 0, 0);
                acc[0][ni] = __builtin_amdgcn_mfma_f32_16x16x32_bf16(ah0, blf[ni], acc[0][ni], 0, 0, 0);
                acc[0][ni] = __builtin_amdgcn_mfma_f32_16x16x32_bf16(al0, bhf[ni], acc[0][ni], 0, 0, 0);
                acc[1][ni] = __builtin_amdgcn_mfma_f32_16x16x32_bf16(ah1, bhf[ni], acc[1][ni], 0, 0, 0);
                acc[1][ni] = __builtin_amdgcn_mfma_f32_16x16x32_bf16(ah1, blf[ni], acc[1][ni], 0, 0, 0);
                acc[1][ni] = __builtin_amdgcn_mfma_f32_16x16x32_bf16(al1, bhf[ni], acc[1][ni], 0, 0, 0);
            }
            __builtin_amdgcn_s_setprio(0);
        }
        __builtin_amdgcn_s_barrier();

        // ---- phases 1..3: (phase 1 stages B(t+1)); A-pair reads + 24 MFMA
#pragma unroll
        for (int p = 1; p < 4; ++p) {
            if (p == 1 && st) STG_B(bw, kn);
            const int m0 = 2 * p;
            s8v ah0 = *(const s8v*)(br + aoff + m0 * 512);
            s8v al0 = *(const s8v*)(br + 8192 + aoff + m0 * 512);
            s8v ah1 = *(const s8v*)(br + aoff + (m0 + 1) * 512);
            s8v al1 = *(const s8v*)(br + 8192 + aoff + (m0 + 1) * 512);
            __builtin_amdgcn_s_setprio(1);
#pragma unroll
            for (int ni = 0; ni < 4; ++ni) {
                acc[m0][ni] = __builtin_amdgcn_mfma_f32_16x16x32_bf16(ah0, bhf[ni], acc[m0][ni], 0, 0, 0);
                acc[m0][ni] = __builtin_amdgcn_mfma_f32_16x16x32_bf16(ah0, blf[ni], acc[m0][ni], 0, 0, 0);
                acc[m0][ni] = __builtin_amdgcn_mfma_f32_16x16x32_bf16(al0, bhf[ni], acc[m0][ni], 0, 0, 0);
                acc[m0 + 1][ni] = __builtin_amdgcn_mfma_f32_16x16x32_bf16(ah1, bhf[ni], acc[m0 + 1][ni], 0, 0, 0);
                acc[m0 + 1][ni] = __builtin_amdgcn_mfma_f32_16x16x32_bf16(ah1, blf[ni], acc[m0 + 1][ni], 0, 0, 0);
                acc[m0 + 1][ni] = __builtin_amdgcn_mfma_f32_16x16x32_bf16(al1, bhf[ni], acc[m0 + 1][ni], 0, 0, 0);
            }
            __builtin_amdgcn_s_setprio(0);
            if (p < 3) __builtin_amdgcn_s_barrier();
        }

        __syncthreads();   // vmcnt(0)+lgkmcnt(0)+barrier: t+1 staged, reads done
        cur ^= 1;
    }
#undef STG_A
#undef STG_B

    const int fr = (lane >> 4) * 4;   // C/D: row = (lane>>4)*4 + reg
    const int fc = lane & 15;         //      col = lane & 15

    if constexpr (OUT == 2) {
#pragma unroll
        for (int mi = 0; mi < 8; ++mi)
#pragma unroll
            for (int ni = 0; ni < 4; ++ni) {
                size_t rbase = row0 + wm * 128 + mi * 16 + fr;
                size_t cidx = col0 + wn * 64 + ni * 16 + fc;
#pragma unroll
                for (int g = 0; g < 4; ++g) {
                    float o = acc[mi][ni][g];
                    u16 h = f2bf(o);
                    u16 l2 = f2bf(o - bf2f(h));
                    size_t idx = (rbase + g) * 1024 + cidx;
                    Ohi[idx] = h;
                    Olo[idx] = l2;
                }
            }
    } else {
        float bj[4];
#pragma unroll
        for (int ni = 0; ni < 4; ++ni) bj[ni] = bias[col0 + wn * 64 + ni * 16 + fc];
#pragma unroll
        for (int mi = 0; mi < 8; ++mi)
#pragma unroll
            for (int ni = 0; ni < 4; ++ni) {
                size_t rbase = row0 + wm * 128 + mi * 16 + fr;
                size_t cidx = col0 + wn * 64 + ni * 16 + fc;
#pragma unroll
                for (int g = 0; g < 4; ++g)
                    C[(rbase + g) * (size_t)ldc + cidx] = acc[mi][ni][g] + bj[ni];
            }
    }
}

// ---------------- fused MFMA attention (unchanged) -------------------------
__global__ __launch_bounds__(256) void fattn_k(const u16* __restrict__ Qhi,
                                               const u16* __restrict__ Qlo,
                                               const u16* __restrict__ Khi,
                                               const u16* __restrict__ Klo,
                                               const u16* __restrict__ Vthi,
                                               const u16* __restrict__ Vtlo,
                                               const float2* __restrict__ tab,
                                               u16* __restrict__ Phi,
                                               u16* __restrict__ Plo) {
    __shared__ u16 zh[64 * 256];     // 32 KB  [tokL][cl], 16B-unit ^ (tokL&7)
    __shared__ u16 zl[64 * 256];     // 32 KB
    __shared__ float lpart[4][64];
    __shared__ float invl[64];

    const int tid = threadIdx.x;
    const int lane = tid & 63;
    const int w = tid >> 6;
    const int g = lane >> 4;
    const int l15 = lane & 15;
    const int hh = blockIdx.y, bb = blockIdx.z;
    const int bh = bb * 16 + hh;
    const int tok0 = blockIdx.x * 64;

    // ---- Q^T B-frags ----
    s8v qf[2][4][2];   // [ks][cf][hi/lo]
#pragma unroll
    for (int cf = 0; cf < 4; ++cf)
#pragma unroll
        for (int ks = 0; ks < 2; ++ks) {
            size_t qo = ((size_t)(bb * NN + tok0 + cf * 16 + l15)) * 1024
                        + hh * 64 + ks * 32 + g * 8;
            qf[ks][cf][0] = *(const s8v*)(Qhi + qo);
            qf[ks][cf][1] = *(const s8v*)(Qlo + qo);
        }

    // ---- QK^T ----
    f32x4 acc[4][4] = {};
    const size_t kbase = (size_t)bh * NCL * 64;
#pragma unroll
    for (int f = 0; f < 4; ++f) {
        const int cl = w * 64 + f * 16 + l15;
        s8v kf[2][2];
#pragma unroll
        for (int ks = 0; ks < 2; ++ks) {
            size_t ko = kbase + (size_t)cl * 64 + (((ks * 4 + g) ^ (l15 & 7)) << 3);
            kf[ks][0] = *(const s8v*)(Khi + ko);
            kf[ks][1] = *(const s8v*)(Klo + ko);
        }
#pragma unroll
        for (int cf = 0; cf < 4; ++cf)
#pragma unroll
            for (int ks = 0; ks < 2; ++ks) {
                acc[f][cf] = __builtin_amdgcn_mfma_f32_16x16x32_bf16(kf[ks][0], qf[ks][cf][0], acc[f][cf], 0, 0, 0);
                acc[f][cf] = __builtin_amdgcn_mfma_f32_16x16x32_bf16(kf[ks][0], qf[ks][cf][1], acc[f][cf], 0, 0, 0);
                acc[f][cf] = __builtin_amdgcn_mfma_f32_16x16x32_bf16(kf[ks][1], qf[ks][cf][0], acc[f][cf], 0, 0, 0);
            }
    }

    // ---- softmax weights ----
    float lp[4] = {0.f, 0.f, 0.f, 0.f};
#pragma unroll
    for (int f = 0; f < 4; ++f) {
        float2 t4[4];
#pragma unroll
        for (int r = 0; r < 4; ++r)
            t4[r] = tab[bb * NCL + w * 64 + f * 16 + 4 * g + r];
#pragma unroll
        for (int cf = 0; cf < 4; ++cf) {
            float z[4];
#pragma unroll
            for (int r = 0; r < 4; ++r) {
                float e = __expf(acc[f][cf][r] * t4[r].x);
                lp[cf] += t4[r].y * e;
                z[r] = t4[r].y > 0.f ? e : 0.f;
            }
            const int tokL = cf * 16 + l15;
            int idx = (tokL * 256 + w * 64 + f * 16 + 4 * g) ^ (8 * (l15 & 7));
            uint2 ph, pl;
            u16 h0 = f2bf(z[0]), h1 = f2bf(z[1]), h2 = f2bf(z[2]), h3 = f2bf(z[3]);
            ph.x = (unsigned int)h0 | ((unsigned int)h1 << 16);
            ph.y = (unsigned int)h2 | ((unsigned int)h3 << 16);
            pl.x = (unsigned int)f2bf(z[0] - bf2f(h0)) | ((unsigned int)f2bf(z[1] - bf2f(h1)) << 16);
            pl.y = (unsigned int)f2bf(z[2] - bf2f(h2)) | ((unsigned int)f2bf(z[3] - bf2f(h3)) << 16);
            *(uint2*)&zh[idx] = ph;
            *(uint2*)&zl[idx] = pl;
        }
    }
#pragma unroll
    for (int cf = 0; cf < 4; ++cf) {
        lp[cf] += __shfl_xor(lp[cf], 16);
        lp[cf] += __shfl_xor(lp[cf], 32);
    }
    if (lane < 16) {
#pragma unroll
        for (int cf = 0; cf < 4; ++cf) lpart[w][cf * 16 + lane] = lp[cf];
    }
    __syncthreads();

    if (w == 0)
        invl[lane] = 1.f / (lpart[0][lane] + lpart[1][lane] + lpart[2][lane] + lpart[3][lane]);

    // ---- PV ----
    f32x4 oacc[4] = {};
    const size_t vbase = (size_t)bh * 64 * 256;
    const int dg = w * 16 + l15;
#pragma unroll
    for (int ks = 0; ks < 8; ++ks) {
        size_t vo = vbase + (size_t)dg * 256
                    + (((ks * 4 + g) & 24) | (((ks * 4 + g) ^ dg) & 7)) * 8;
        s8v va = *(const s8v*)(Vthi + vo);
        s8v vb = *(const s8v*)(Vtlo + vo);
#pragma unroll
        for (int cf = 0; cf < 4; ++cf) {
            int idx = ((cf * 16 + l15) * 256 + ks * 32 + g * 8) ^ (8 * (l15 & 7));
            s8v zhf = *(const s8v*)&zh[idx];
            s8v zlf = *(const s8v*)&zl[idx];
            oacc[cf] = __builtin_amdgcn_mfma_f32_16x16x32_bf16(va, zhf, oacc[cf], 0, 0, 0);
            oacc[cf] = __builtin_amdgcn_mfma_f32_16x16x32_bf16(va, zlf, oacc[cf], 0, 0, 0);
            oacc[cf] = __builtin_amdgcn_mfma_f32_16x16x32_bf16(vb, zhf, oacc[cf], 0, 0, 0);
        }
    }
    __syncthreads();

    // ---- epilogue ----
#pragma unroll
    for (int cf = 0; cf < 4; ++cf) {
        const int tokL = cf * 16 + l15;
        float il = invl[tokL];
        float o0 = oacc[cf][0] * il, o1 = oacc[cf][1] * il;
        float o2 = oacc[cf][2] * il, o3 = oacc[cf][3] * il;
        u16 h0 = f2bf(o0), h1 = f2bf(o1), h2 = f2bf(o2), h3 = f2bf(o3);
        uint2 ph, pl;
        ph.x = (unsigned int)h0 | ((unsigned int)h1 << 16);
        ph.y = (unsigned int)h2 | ((unsigned int)h3 << 16);
        pl.x = (unsigned int)f2bf(o0 - bf2f(h0)) | ((unsigned int)f2bf(o1 - bf2f(h1)) << 16);
        pl.y = (unsigned int)f2bf(o2 - bf2f(h2)) | ((unsigned int)f2bf(o3 - bf2f(h3)) << 16);
        size_t po = ((size_t)(bb * NN + tok0 + tokL)) * 1024 + hh * 64 + w * 16 + 4 * g;
        *(uint2*)(Phi + po) = ph;
        *(uint2*)(Plo + po) = pl;
    }
}

// ---------------- launcher -------------------------------------------------
extern "C" void kernel_launch(void* const* d_in, const int* in_sizes, int n_in,
                              void* d_out, int out_size, void* d_ws, size_t ws_size,
                              hipStream_t stream) {
    const int* cluster  = (const int*)d_in[0];
    const float* x      = (const float*)d_in[1];
    const float* w_q    = (const float*)d_in[2];
    const float* w_kv   = (const float*)d_in[3];
    const float* w_proj = (const float*)d_in[4];
    const float* b_proj = (const float*)d_in[5];
    float* out = (float*)d_out;

    // layout (~312 MiB)
    const size_t SZ_H  = (size_t)MM * 1024 * 2;      // 64 MiB
    const size_t SZ_W  = (size_t)4096 * 1024 * 2;    // 8 MiB
    const size_t SZ_XS = (size_t)2048 * 1024 * 2;    // 4 MiB
    const size_t SZ_CS = (size_t)2048 * 2048 * 4;    // 16 MiB
    const size_t SZ_KV = (size_t)128 * NCL * 64 * 2; // 4 MiB

    char* p = (char*)d_ws;
    u16* Xhi = (u16*)p;   p += SZ_H;    // reused as Phi after attention
    u16* Xlo = (u16*)p;   p += SZ_H;    // reused as Plo
    u16* Qhi = (u16*)p;   p += SZ_H;
    u16* Qlo = (u16*)p;   p += SZ_H;
    u16* Wthi = (u16*)p;  p += SZ_W;
    u16* Wtlo = (u16*)p;  p += SZ_W;
    u16* XShi = (u16*)p;  p += SZ_XS;
    u16* XSlo = (u16*)p;  p += SZ_XS;
    float* Csum = (float*)p; p += SZ_CS;
    u16* Khi = (u16*)p;   p += SZ_KV;
    u16* Klo = (u16*)p;   p += SZ_KV;
    u16* Vthi = (u16*)p;  p += SZ_KV;
    u16* Vtlo = (u16*)p;  p += SZ_KV;
    float2* tab = (float2*)p; p += 2048 * sizeof(float2);
    int* counts = (int*)p;   p += 2048 * sizeof(int);
    int* tokidx = (int*)p;   p += (size_t)BB * NN * sizeof(int);
    int* starts = (int*)p;

    hipMemsetAsync(counts, 0, BB * NCL * sizeof(int), stream);
    count_k<<<MM / 256, 256, 0, stream>>>(cluster, counts);
    tab_k<<<8, 256, 0, stream>>>(counts, tab);
    sortidx_k<<<BB, 256, 0, stream>>>(cluster, counts, tokidx, starts);

    convx_k<<<(size_t)MM * KK / 1024, 256, 0, stream>>>(x, Xhi, Xlo);
    convw_k<<<dim3(32, 32), 256, 0, stream>>>(w_q, 1024, Wthi, Wtlo);
    convw_k<<<dim3(64, 32), 256, 0, stream>>>(w_kv, 2048, Wthi + (size_t)1024 * KK, Wtlo + (size_t)1024 * KK);
    convw_k<<<dim3(32, 32), 256, 0, stream>>>(w_proj, 1024, Wthi + (size_t)3072 * KK, Wtlo + (size_t)3072 * KK);

    xsum2_k<<<BB * NCL, 256, 0, stream>>>(x, tokidx, starts, counts, XShi, XSlo);

    // Q = X @ Wq^T  -> bf16 hi/lo  (256-tile 8-wave phased, XCD-swizzled)
    hgemm256_k<2><<<512, 512, 0, stream>>>(Xhi, Xlo, Wthi, Wtlo,
                                           nullptr, 0, nullptr, Qhi, Qlo);
    // Csum = XS @ Wkv^T (ksum | vsum), fp32 (small: keep 128-tile kernel)
    hgemm_k<0><<<dim3(16, 16), 256, 0, stream>>>(XShi, XSlo,
                                                 Wthi + (size_t)1024 * KK, Wtlo + (size_t)1024 * KK,
                                                 Csum, 2048, nullptr, nullptr, nullptr);
    // K / V^T in MFMA-friendly pre-swizzled layouts
    convk_k<<<128, 256, 0, stream>>>(Csum, Khi, Klo);
    convv_k<<<128, 256, 0, stream>>>(Csum, Vthi, Vtlo);

    // fused attention -> P (bf16 hi/lo, aliases X buffers)
    fattn_k<<<dim3(64, HEADS, BB), 256, 0, stream>>>(Qhi, Qlo, Khi, Klo,
                                                     Vthi, Vtlo, tab, Xhi, Xlo);
    // out = P @ Wproj^T + bias  (256-tile 8-wave phased, XCD-swizzled)
    hgemm256_k<1><<<512, 512, 0, stream>>>(Xhi, Xlo,
                                           Wthi + (size_t)3072 * KK, Wtlo + (size_t)3072 * KK,
                                           out, 1024, b_proj, nullptr, nullptr);
}